// Round 6
// baseline (191.355 us; speedup 1.0000x reference)
//
#include <hip/hip_runtime.h>
#include <math.h>

typedef __attribute__((ext_vector_type(8))) short short8;   // 8 x bf16 (4 VGPRs)
typedef __attribute__((ext_vector_type(4))) float f32x4;    // MFMA acc

constexpr int B  = 8;
constexpr int N  = 1024;
constexpr int D  = 512;
constexpr int H  = 8;
constexpr int DH = 64;
constexpr int M_ROWS = 8192;
constexpr float EPS_DIST = 1e-8f;
constexpr float EPS_LN   = 1e-5f;

// fp32 -> bf16 bits (RNE)
__device__ inline unsigned short bfbits(float f) {
    union { float f; unsigned u; } v; v.f = f;
    unsigned r = v.u + 0x7fffu + ((v.u >> 16) & 1u);
    return (unsigned short)(r >> 16);
}
__device__ inline float bf2f(unsigned short s) {
    union { unsigned u; float f; } v; v.u = ((unsigned)s) << 16; return v.f;
}

// async 16B global->LDS (per lane; LDS dest = wave-uniform base + lane*16)
__device__ inline void async_ld16(unsigned short* lds, const unsigned short* g) {
    __builtin_amdgcn_global_load_lds(
        (const __attribute__((address_space(1))) unsigned int*)(g),
        (__attribute__((address_space(3))) unsigned int*)(lds),
        16, 0, 0);
}

__device__ inline float block_sum256(float s, float* red) {
    for (int o = 32; o > 0; o >>= 1) s += __shfl_down(s, o, 64);
    int lane = threadIdx.x & 63, wid = threadIdx.x >> 6;
    if (lane == 0) red[wid] = s;
    __syncthreads();
    if (threadIdx.x == 0) red[4] = red[0] + red[1] + red[2] + red[3];
    __syncthreads();
    return red[4];
}

// ---------------------------------------------------------------------------
// Fused: blocks 0..255 transpose+convert the 4 weights to bf16;
// blocks 256..8447 do LN1 (x -> h bf16).
// ---------------------------------------------------------------------------
__global__ __launch_bounds__(256) void prep_kernel(const float* __restrict__ Wq,
                                                   const float* __restrict__ Wk,
                                                   const float* __restrict__ Wv,
                                                   const float* __restrict__ Wo,
                                                   unsigned short* __restrict__ WtAll,
                                                   const float* __restrict__ x,
                                                   const float* __restrict__ ln1_g,
                                                   const float* __restrict__ ln1_b,
                                                   unsigned short* __restrict__ h_bf) {
    __shared__ float red[8];
    const int bxg = blockIdx.x;
    if (bxg < 256) {
        int sub = bxg >> 6;
        const float* W = sub == 0 ? Wq : sub == 1 ? Wk : sub == 2 ? Wv : Wo;
        unsigned short* Wt = WtAll + (size_t)sub * 262144;
        int t = (bxg & 63) * 256 + threadIdx.x;
        int tn = t & 127, tk = t >> 7;
        int k = tk * 4, n = tn * 4;
        float4 r0 = *(const float4*)&W[(size_t)(k + 0) * 512 + n];
        float4 r1 = *(const float4*)&W[(size_t)(k + 1) * 512 + n];
        float4 r2 = *(const float4*)&W[(size_t)(k + 2) * 512 + n];
        float4 r3 = *(const float4*)&W[(size_t)(k + 3) * 512 + n];
        ushort4 c;
        c.x = bfbits(r0.x); c.y = bfbits(r1.x); c.z = bfbits(r2.x); c.w = bfbits(r3.x);
        *(ushort4*)&Wt[(size_t)(n + 0) * 512 + k] = c;
        c.x = bfbits(r0.y); c.y = bfbits(r1.y); c.z = bfbits(r2.y); c.w = bfbits(r3.y);
        *(ushort4*)&Wt[(size_t)(n + 1) * 512 + k] = c;
        c.x = bfbits(r0.z); c.y = bfbits(r1.z); c.z = bfbits(r2.z); c.w = bfbits(r3.z);
        *(ushort4*)&Wt[(size_t)(n + 2) * 512 + k] = c;
        c.x = bfbits(r0.w); c.y = bfbits(r1.w); c.z = bfbits(r2.w); c.w = bfbits(r3.w);
        *(ushort4*)&Wt[(size_t)(n + 3) * 512 + k] = c;
    } else {
        const int row = bxg - 256;
        const int t = threadIdx.x;
        const float* xr = x + (size_t)row * D;
        float v0 = xr[t], v1 = xr[t + 256];
        float mu = block_sum256(v0 + v1, red) * (1.0f / D);
        float d0 = v0 - mu, d1 = v1 - mu;
        float var = block_sum256(d0 * d0 + d1 * d1, red) * (1.0f / D);
        float rstd = rsqrtf(var + EPS_LN);
        h_bf[(size_t)row * D + t]       = bfbits(d0 * rstd * ln1_g[t] + ln1_b[t]);
        h_bf[(size_t)row * D + t + 256] = bfbits(d1 * rstd * ln1_g[t + 256] + ln1_b[t + 256]);
    }
}

// ---------------------------------------------------------------------------
// MTx128-tile bf16 MFMA GEMM, BK=64. A[M,512] @ Wt[n][k]. 1D grid, by=id&(RB-1)
// (XCD-local A reuse). Fused QKV epilogue (N=1536): Q,K -> [bh][n][dh] + sumsq,
// V -> [bh][dh][n] via LDS transpose.
// ---------------------------------------------------------------------------
template <int MT>
__global__ __launch_bounds__(256) void gemm_qkv(const unsigned short* __restrict__ A,
                                                const unsigned short* __restrict__ Wt,
                                                const float* __restrict__ bias0,
                                                const float* __restrict__ bias1,
                                                const float* __restrict__ bias2,
                                                unsigned short* __restrict__ Qo,
                                                unsigned short* __restrict__ Ko,
                                                unsigned short* __restrict__ Vo,
                                                float* __restrict__ sq0,
                                                float* __restrict__ sq1) {
    constexpr int RB = M_ROWS / MT;
    constexpr int NI = MT / 32;
    constexpr int ASZ = MT * 64, BSZ = 128 * 64;
    constexpr int SMSZ = (ASZ + BSZ > 18432) ? ASZ + BSZ : 18432;
    __shared__ unsigned short smem[SMSZ];
    unsigned short* As = smem;
    unsigned short* Bs = smem + ASZ;

    const int id = blockIdx.x;
    const int by = id & (RB - 1), bx = id / RB;
    const int tid = threadIdx.x;
    const int lane = tid & 63, wv = tid >> 6;
    const int quad = lane >> 4, l15 = lane & 15;
    const int row0 = by * MT, col0 = bx * 128;
    const int wm = (wv & 1) * (MT / 2), wn = (wv >> 1) * 64;

    f32x4 acc[NI][4];
    #pragma unroll
    for (int i = 0; i < NI; ++i)
        #pragma unroll
        for (int j = 0; j < 4; ++j) acc[i][j] = (f32x4){0.f, 0.f, 0.f, 0.f};

    const unsigned short* Ag = A  + (size_t)row0 * 512;
    const unsigned short* Bg = Wt + (size_t)col0 * 512;

    for (int k0 = 0; k0 < 512; k0 += 64) {
        __syncthreads();
        #pragma unroll
        for (int c = 0; c < ASZ / 2048; ++c) {
            int fu = c * 2048 + tid * 8;
            int r = fu >> 6, ko = fu & 63;
            async_ld16(As + fu, Ag + (size_t)r * 512 + k0 + ko);
        }
        #pragma unroll
        for (int c = 0; c < BSZ / 2048; ++c) {
            int fu = c * 2048 + tid * 8;
            int r = fu >> 6, ko = fu & 63;
            async_ld16(Bs + fu, Bg + (size_t)r * 512 + k0 + ko);
        }
        __syncthreads();

        #pragma unroll
        for (int ks = 0; ks < 2; ++ks) {
            short8 af[NI], bf[4];
            #pragma unroll
            for (int i = 0; i < NI; ++i)
                af[i] = *(const short8*)&As[(wm + i * 16 + l15) * 64 + ks * 32 + quad * 8];
            #pragma unroll
            for (int j = 0; j < 4; ++j)
                bf[j] = *(const short8*)&Bs[(wn + j * 16 + l15) * 64 + ks * 32 + quad * 8];
            #pragma unroll
            for (int i = 0; i < NI; ++i)
                #pragma unroll
                for (int j = 0; j < 4; ++j)
                    acc[i][j] = __builtin_amdgcn_mfma_f32_16x16x32_bf16(af[i], bf[j], acc[i][j], 0, 0, 0);
        }
    }

    const int colg = col0 + wn;
    const int seg = colg >> 9;                 // 0=Q 1=K 2=V
    const int hh = (colg & 511) >> 6;
    const float* bias = seg == 0 ? bias0 : seg == 1 ? bias1 : bias2;

    if (seg < 2) {
        unsigned short* dst = seg == 0 ? Qo : Ko;
        float* sq = seg == 0 ? sq0 : sq1;
        #pragma unroll
        for (int i = 0; i < NI; ++i) {
            const int m0 = row0 + wm + i * 16 + quad * 4;
            float ss[4] = {0.f, 0.f, 0.f, 0.f};
            #pragma unroll
            for (int j = 0; j < 4; ++j) {
                float bvj = bias[hh * 64 + j * 16 + l15];
                #pragma unroll
                for (int r = 0; r < 4; ++r) {
                    float v = acc[i][j][r] + bvj;
                    unsigned short ub = bfbits(v);
                    float vr = bf2f(ub);
                    ss[r] += vr * vr;
                    int m = m0 + r;
                    int b_ = m >> 10, n_ = m & 1023;
                    dst[((size_t)((b_ * 8 + hh) * 1024) + n_) * 64 + j * 16 + l15] = ub;
                }
            }
            #pragma unroll
            for (int r = 0; r < 4; ++r) {
                float s = ss[r];
                s += __shfl_xor(s, 1, 64);
                s += __shfl_xor(s, 2, 64);
                s += __shfl_xor(s, 4, 64);
                s += __shfl_xor(s, 8, 64);
                if (l15 == 0) {
                    int m = m0 + r;
                    sq[(size_t)((m >> 10) * 8 + hh) * 1024 + (m & 1023)] = s;
                }
            }
        }
    } else {
        // V: transpose through per-wave LDS region, then coalesced stores
        __syncthreads();   // whole block is V (uniform): safe
        unsigned short* T = smem + wv * 4608;  // [64 d][72]
        #pragma unroll
        for (int i = 0; i < NI; ++i)
            #pragma unroll
            for (int j = 0; j < 4; ++j) {
                float bvj = bias[hh * 64 + j * 16 + l15];
                ushort4 pk;
                pk.x = bfbits(acc[i][j][0] + bvj);
                pk.y = bfbits(acc[i][j][1] + bvj);
                pk.z = bfbits(acc[i][j][2] + bvj);
                pk.w = bfbits(acc[i][j][3] + bvj);
                *(ushort4*)&T[(j * 16 + l15) * 72 + i * 16 + quad * 4] = pk;
            }
        const int b_ = (row0 + wm) >> 10;
        const int nbase = (row0 + wm) & 1023;
        unsigned short* Vg = Vo + ((size_t)((b_ * 8 + hh) * 64)) * 1024 + nbase;
        #pragma unroll
        for (int it = 0; it < 8; ++it) {
            int dl = it * 8 + (lane >> 3);
            int nl = (lane & 7) * 8;
            uint4 v = *(const uint4*)&T[dl * 72 + nl];
            *(uint4*)&Vg[(size_t)dl * 1024 + nl] = v;
        }
    }
}

// ---------------------------------------------------------------------------
// MFMA distance attention. Block = 8 waves (512 thr), 128 q rows (16 q/wave)
// per (b,h). V pre-transposed [bh][dh][n]. Double-buffered K/V + register
// prefetch; one barrier per key-tile. bh = id&63 -> same-head blocks same XCD.
// ---------------------------------------------------------------------------
__global__ __launch_bounds__(512) void attn_kernel(const unsigned short* __restrict__ Q,
                                                   const unsigned short* __restrict__ K,
                                                   const unsigned short* __restrict__ Vt,
                                                   const float* __restrict__ qsq,
                                                   const float* __restrict__ ksq,
                                                   unsigned short* __restrict__ O) {
    __shared__ unsigned short Ks[2][64][72];
    __shared__ unsigned short Vs[2][64][72];
    __shared__ unsigned short Ps[8][16][72];
    __shared__ float ksq_s[2][64];

    const int id = blockIdx.x;
    const int bh = id & 63, qb = id >> 6;
    const int q0 = qb * 128;
    const int tid = threadIdx.x;
    const int lane = tid & 63, w = tid >> 6;
    const int quad = lane >> 4, l15 = lane & 15;
    const int b_ = bh >> 3, h_ = bh & 7;

    const unsigned short* Qb = Q  + (size_t)bh * N * DH;
    const unsigned short* Kb = K  + (size_t)bh * N * DH;
    const unsigned short* Vb = Vt + (size_t)bh * DH * N;

    short8 qf0, qf1;
    {
        const unsigned short* qp = Qb + (size_t)(q0 + w * 16 + l15) * 64 + quad * 8;
        qf0 = *(const short8*)qp;
        qf1 = *(const short8*)(qp + 32);
    }
    float qe[4];
    #pragma unroll
    for (int r = 0; r < 4; ++r)
        qe[r] = qsq[bh * N + q0 + w * 16 + quad * 4 + r] + EPS_DIST;

    f32x4 oacc[4];
    #pragma unroll
    for (int dt = 0; dt < 4; ++dt) oacc[dt] = (f32x4){0.f, 0.f, 0.f, 0.f};
    float dpart[4] = {};

    const int rr = tid >> 3, cc = (tid & 7) * 8;
    uint4 kreg, vreg;
    float ksreg = 0.f;

    kreg = *(const uint4*)(Kb + (size_t)rr * 64 + cc);
    vreg = *(const uint4*)(Vb + (size_t)rr * N + cc);
    if (tid < 64) ksreg = ksq[bh * N + tid];

    *(uint4*)&Ks[0][rr][cc] = kreg;
    *(uint4*)&Vs[0][rr][cc] = vreg;
    if (tid < 64) ksq_s[0][tid] = ksreg;
    __syncthreads();

    #pragma unroll 2
    for (int kt = 0; kt < 16; ++kt) {
        const int cur = kt & 1;
        if (kt < 15) {
            kreg = *(const uint4*)(Kb + (size_t)((kt + 1) * 64 + rr) * 64 + cc);
            vreg = *(const uint4*)(Vb + (size_t)rr * N + (kt + 1) * 64 + cc);
            if (tid < 64) ksreg = ksq[bh * N + (kt + 1) * 64 + tid];
        }

        // scores + transform -> Ps  (16 q x 64 keys per wave)
        #pragma unroll
        for (int kb = 0; kb < 4; ++kb) {
            short8 kf0 = *(const short8*)&Ks[cur][kb * 16 + l15][quad * 8];
            short8 kf1 = *(const short8*)&Ks[cur][kb * 16 + l15][32 + quad * 8];
            float ks2 = ksq_s[cur][kb * 16 + l15];
            f32x4 sa = (f32x4){0.f, 0.f, 0.f, 0.f};
            sa = __builtin_amdgcn_mfma_f32_16x16x32_bf16(qf0, kf0, sa, 0, 0, 0);
            sa = __builtin_amdgcn_mfma_f32_16x16x32_bf16(qf1, kf1, sa, 0, 0, 0);
            #pragma unroll
            for (int r = 0; r < 4; ++r) {
                float d2 = fmaf(-2.0f, sa[r], qe[r] + ks2);
                d2 = fmaxf(d2, EPS_DIST);
                float p = __expf(-__builtin_amdgcn_sqrtf(d2));
                dpart[r] += p;
                union { float f; unsigned u; } pu; pu.f = p;
                Ps[w][quad * 4 + r][kb * 16 + l15] = (unsigned short)(pu.u >> 16);
            }
        }

        // PV
        short8 vf[4][2];
        #pragma unroll
        for (int dt = 0; dt < 4; ++dt)
            #pragma unroll
            for (int kc = 0; kc < 2; ++kc)
                vf[dt][kc] = *(const short8*)&Vs[cur][dt * 16 + l15][kc * 32 + quad * 8];
        #pragma unroll
        for (int kc = 0; kc < 2; ++kc) {
            short8 pf = *(const short8*)&Ps[w][l15][kc * 32 + quad * 8];
            #pragma unroll
            for (int dt = 0; dt < 4; ++dt)
                oacc[dt] = __builtin_amdgcn_mfma_f32_16x16x32_bf16(pf, vf[dt][kc], oacc[dt], 0, 0, 0);
        }

        if (kt < 15) {
            *(uint4*)&Ks[cur ^ 1][rr][cc] = kreg;
            *(uint4*)&Vs[cur ^ 1][rr][cc] = vreg;
            if (tid < 64) ksq_s[cur ^ 1][tid] = ksreg;
        }
        __syncthreads();
    }

    float rinv[4];
    #pragma unroll
    for (int r = 0; r < 4; ++r) {
        float s = dpart[r];
        s += __shfl_xor(s, 1, 64);
        s += __shfl_xor(s, 2, 64);
        s += __shfl_xor(s, 4, 64);
        s += __shfl_xor(s, 8, 64);
        rinv[r] = 1.0f / s;
    }

    #pragma unroll
    for (int dt = 0; dt < 4; ++dt)
        #pragma unroll
        for (int r = 0; r < 4; ++r) {
            int n_ = q0 + w * 16 + quad * 4 + r;
            O[((size_t)(b_ * N + n_) * D) + h_ * DH + dt * 16 + l15] =
                bfbits(oacc[dt][r] * rinv[r]);
        }
}

// ---------------------------------------------------------------------------
// Fused out-proj + residual + LN2. Block = 512 thr (8 waves) handles 32 rows
// x ALL 512 cols: wave w -> rows (w&1)*16, col-quarter (w>>1)*128 (8 col-tiles).
// K-loop BK=32 over Wo. Epilogue: v = acc + bo + x; LN across the row via
// 16-lane shuffle + cross-wave LDS combine; fp32 out.
// ---------------------------------------------------------------------------
__global__ __launch_bounds__(512) void outln_kernel(const unsigned short* __restrict__ Ob,
                                                    const unsigned short* __restrict__ WtO,
                                                    const float* __restrict__ bo,
                                                    const float* __restrict__ x,
                                                    const float* __restrict__ gamma,
                                                    const float* __restrict__ beta,
                                                    float* __restrict__ out) {
    __shared__ unsigned short As[32 * 40];     // [row][k] pad 40
    __shared__ unsigned short Bs[512 * 40];    // [col][k] pad 40
    __shared__ float redS[32][4];
    __shared__ float redQ[32][4];

    const int m0 = blockIdx.x * 32;
    const int tid = threadIdx.x;
    const int lane = tid & 63, w = tid >> 6;
    const int quad = lane >> 4, l15 = lane & 15;
    const int wr = (w & 1) * 16;               // row offset in block
    const int wc = (w >> 1) * 128;             // col offset

    f32x4 acc[8];
    #pragma unroll
    for (int j = 0; j < 8; ++j) acc[j] = (f32x4){0.f, 0.f, 0.f, 0.f};

    const unsigned short* Ag = Ob + (size_t)m0 * 512;

    for (int k0 = 0; k0 < 512; k0 += 32) {
        __syncthreads();
        // stage B: 512 cols x 32 k (each thread: one col row, 4 x 16B)
        #pragma unroll
        for (int c = 0; c < 4; ++c)
            *(uint4*)&Bs[tid * 40 + c * 8] = *(const uint4*)&WtO[(size_t)tid * 512 + k0 + c * 8];
        // stage A: 32 rows x 32 k (threads 0..127)
        if (tid < 128) {
            int r = tid >> 2, c = tid & 3;
            *(uint4*)&As[r * 40 + c * 8] = *(const uint4*)&Ag[(size_t)r * 512 + k0 + c * 8];
        }
        __syncthreads();

        short8 af = *(const short8*)&As[(wr + l15) * 40 + quad * 8];
        #pragma unroll
        for (int j = 0; j < 8; ++j) {
            short8 bf = *(const short8*)&Bs[(wc + j * 16 + l15) * 40 + quad * 8];
            acc[j] = __builtin_amdgcn_mfma_f32_16x16x32_bf16(af, bf, acc[j], 0, 0, 0);
        }
    }

    // epilogue: v = acc + bias + x; LN over full row
    float bv[8], gv[8], bev[8];
    #pragma unroll
    for (int j = 0; j < 8; ++j) {
        int col = wc + j * 16 + l15;
        bv[j] = bo[col]; gv[j] = gamma[col]; bev[j] = beta[col];
    }

    float v[8][4];
    float s1[4] = {0.f, 0.f, 0.f, 0.f}, s2[4] = {0.f, 0.f, 0.f, 0.f};
    #pragma unroll
    for (int r = 0; r < 4; ++r) {
        int m = m0 + wr + quad * 4 + r;
        #pragma unroll
        for (int j = 0; j < 8; ++j) {
            float t = acc[j][r] + bv[j] + x[(size_t)m * 512 + wc + j * 16 + l15];
            v[j][r] = t;
            s1[r] += t;
            s2[r] += t * t;
        }
    }
    #pragma unroll
    for (int r = 0; r < 4; ++r) {
        #pragma unroll
        for (int o = 1; o < 16; o <<= 1) {
            s1[r] += __shfl_xor(s1[r], o, 64);
            s2[r] += __shfl_xor(s2[r], o, 64);
        }
    }
    if (l15 == 0) {
        #pragma unroll
        for (int r = 0; r < 4; ++r) {
            redS[wr + quad * 4 + r][w >> 1] = s1[r];
            redQ[wr + quad * 4 + r][w >> 1] = s2[r];
        }
    }
    __syncthreads();
    #pragma unroll
    for (int r = 0; r < 4; ++r) {
        int lr = wr + quad * 4 + r;
        float S = redS[lr][0] + redS[lr][1] + redS[lr][2] + redS[lr][3];
        float Q2 = redQ[lr][0] + redQ[lr][1] + redQ[lr][2] + redQ[lr][3];
        float mu = S * (1.0f / 512.0f);
        float var = Q2 * (1.0f / 512.0f) - mu * mu;
        float rstd = rsqrtf(var + EPS_LN);
        int m = m0 + lr;
        #pragma unroll
        for (int j = 0; j < 8; ++j)
            out[(size_t)m * 512 + wc + j * 16 + l15] =
                (v[j][r] - mu) * rstd * gv[j] + bev[j];
    }
}

// ---------------------------------------------------------------------------
extern "C" void kernel_launch(void* const* d_in, const int* in_sizes, int n_in,
                              void* d_out, int out_size, void* d_ws, size_t ws_size,
                              hipStream_t stream) {
    const float* x     = (const float*)d_in[0];
    const float* Wq    = (const float*)d_in[1];
    const float* Wk    = (const float*)d_in[2];
    const float* Wv    = (const float*)d_in[3];
    const float* Wo    = (const float*)d_in[4];
    const float* bq    = (const float*)d_in[5];
    const float* bk    = (const float*)d_in[6];
    const float* bv    = (const float*)d_in[7];
    const float* bo    = (const float*)d_in[8];
    const float* ln1_g = (const float*)d_in[9];
    const float* ln1_b = (const float*)d_in[10];
    const float* ln2_g = (const float*)d_in[11];
    const float* ln2_b = (const float*)d_in[12];
    float* out = (float*)d_out;

    unsigned short* WtAll = (unsigned short*)d_ws;    // [4][512][512] bf16
    unsigned short* h_bf  = WtAll + 4 * 262144;       // [8192][512]
    unsigned short* Qb    = h_bf + 4194304;           // [64][1024][64]
    unsigned short* Kb    = Qb + 4194304;
    unsigned short* Vtg   = Kb + 4194304;             // [64][64][1024] transposed
    unsigned short* Ob    = Vtg + 4194304;            // [8192][512]
    float* qsq = (float*)(Ob + 4194304);              // [65536]
    float* ksq = qsq + 65536;

    // 1) weights -> bf16^T  +  LN1 -> bf16 (fused launch)
    prep_kernel<<<256 + M_ROWS, 256, 0, stream>>>(Wq, Wk, Wv, Wo, WtAll,
                                                  x, ln1_g, ln1_b, h_bf);

    // 2) fused QKV projection (N=1536) + scatter + sum-squares
    gemm_qkv<128><<<768, 256, 0, stream>>>(h_bf, WtAll, bq, bk, bv,
                                           Qb, Kb, Vtg, qsq, ksq);

    // 3) MFMA distance attention -> Ob [B,N,D] bf16
    attn_kernel<<<512, 512, 0, stream>>>(Qb, Kb, Vtg, qsq, ksq, Ob);

    // 4) fused out-proj + residual + LN2 -> fp32 out
    outln_kernel<<<256, 512, 0, stream>>>(Ob, WtAll + 3 * 262144, bo,
                                          x, ln2_g, ln2_b, out);
}

// Round 7
// 188.604 us; speedup vs baseline: 1.0146x; 1.0146x over previous
//
#include <hip/hip_runtime.h>
#include <math.h>

typedef __attribute__((ext_vector_type(8))) short short8;   // 8 x bf16 (4 VGPRs)
typedef __attribute__((ext_vector_type(4))) float f32x4;    // MFMA acc

constexpr int B  = 8;
constexpr int N  = 1024;
constexpr int D  = 512;
constexpr int H  = 8;
constexpr int DH = 64;
constexpr int M_ROWS = 8192;
constexpr float EPS_DIST = 1e-8f;
constexpr float EPS_LN   = 1e-5f;

// fp32 -> bf16 bits (RNE)
__device__ inline unsigned short bfbits(float f) {
    union { float f; unsigned u; } v; v.f = f;
    unsigned r = v.u + 0x7fffu + ((v.u >> 16) & 1u);
    return (unsigned short)(r >> 16);
}
__device__ inline float bf2f(unsigned short s) {
    union { unsigned u; float f; } v; v.u = ((unsigned)s) << 16; return v.f;
}

// LDS bank swizzle (stride-64-ushort rows): uses only row bits 0..3, keeps
// 8-ushort (16B) granularity so b128 reads stay aligned.
__device__ inline int swz(int row) {
    return (((row >> 2) & 3) << 4) ^ ((row & 3) << 3);
}

// async 16B global->LDS (per lane; LDS dest = wave-uniform base + lane*16)
__device__ inline void async_ld16(unsigned short* lds, const unsigned short* g) {
    __builtin_amdgcn_global_load_lds(
        (const __attribute__((address_space(1))) unsigned int*)(g),
        (__attribute__((address_space(3))) unsigned int*)(lds),
        16, 0, 0);
}

__device__ inline float block_sum256(float s, float* red) {
    for (int o = 32; o > 0; o >>= 1) s += __shfl_down(s, o, 64);
    int lane = threadIdx.x & 63, wid = threadIdx.x >> 6;
    if (lane == 0) red[wid] = s;
    __syncthreads();
    if (threadIdx.x == 0) red[4] = red[0] + red[1] + red[2] + red[3];
    __syncthreads();
    return red[4];
}

// ---------------------------------------------------------------------------
// Fused: blocks 0..255 transpose+convert the 4 weights to bf16;
// blocks 256..8447 do LN1 (x -> h bf16).
// ---------------------------------------------------------------------------
__global__ __launch_bounds__(256) void prep_kernel(const float* __restrict__ Wq,
                                                   const float* __restrict__ Wk,
                                                   const float* __restrict__ Wv,
                                                   const float* __restrict__ Wo,
                                                   unsigned short* __restrict__ WtAll,
                                                   const float* __restrict__ x,
                                                   const float* __restrict__ ln1_g,
                                                   const float* __restrict__ ln1_b,
                                                   unsigned short* __restrict__ h_bf) {
    __shared__ float red[8];
    const int bxg = blockIdx.x;
    if (bxg < 256) {
        int sub = bxg >> 6;
        const float* W = sub == 0 ? Wq : sub == 1 ? Wk : sub == 2 ? Wv : Wo;
        unsigned short* Wt = WtAll + (size_t)sub * 262144;
        int t = (bxg & 63) * 256 + threadIdx.x;
        int tn = t & 127, tk = t >> 7;
        int k = tk * 4, n = tn * 4;
        float4 r0 = *(const float4*)&W[(size_t)(k + 0) * 512 + n];
        float4 r1 = *(const float4*)&W[(size_t)(k + 1) * 512 + n];
        float4 r2 = *(const float4*)&W[(size_t)(k + 2) * 512 + n];
        float4 r3 = *(const float4*)&W[(size_t)(k + 3) * 512 + n];
        ushort4 c;
        c.x = bfbits(r0.x); c.y = bfbits(r1.x); c.z = bfbits(r2.x); c.w = bfbits(r3.x);
        *(ushort4*)&Wt[(size_t)(n + 0) * 512 + k] = c;
        c.x = bfbits(r0.y); c.y = bfbits(r1.y); c.z = bfbits(r2.y); c.w = bfbits(r3.y);
        *(ushort4*)&Wt[(size_t)(n + 1) * 512 + k] = c;
        c.x = bfbits(r0.z); c.y = bfbits(r1.z); c.z = bfbits(r2.z); c.w = bfbits(r3.z);
        *(ushort4*)&Wt[(size_t)(n + 2) * 512 + k] = c;
        c.x = bfbits(r0.w); c.y = bfbits(r1.w); c.z = bfbits(r2.w); c.w = bfbits(r3.w);
        *(ushort4*)&Wt[(size_t)(n + 3) * 512 + k] = c;
    } else {
        const int row = bxg - 256;
        const int t = threadIdx.x;
        const float* xr = x + (size_t)row * D;
        float v0 = xr[t], v1 = xr[t + 256];
        float mu = block_sum256(v0 + v1, red) * (1.0f / D);
        float d0 = v0 - mu, d1 = v1 - mu;
        float var = block_sum256(d0 * d0 + d1 * d1, red) * (1.0f / D);
        float rstd = rsqrtf(var + EPS_LN);
        h_bf[(size_t)row * D + t]       = bfbits(d0 * rstd * ln1_g[t] + ln1_b[t]);
        h_bf[(size_t)row * D + t + 256] = bfbits(d1 * rstd * ln1_g[t + 256] + ln1_b[t + 256]);
    }
}

// ---------------------------------------------------------------------------
// LN2: y = LN(bf16 Y0 + fp32 x) -> fp32 out
// ---------------------------------------------------------------------------
__global__ __launch_bounds__(256) void ln2_kernel(const unsigned short* __restrict__ y0,
                                                  const float* __restrict__ res,
                                                  const float* __restrict__ gamma,
                                                  const float* __restrict__ beta,
                                                  float* __restrict__ out) {
    __shared__ float red[8];
    const int row = blockIdx.x;
    const int t = threadIdx.x;
    const unsigned short* xr = y0 + (size_t)row * D;
    const float* rr = res + (size_t)row * D;
    float v0 = bf2f(xr[t]) + rr[t];
    float v1 = bf2f(xr[t + 256]) + rr[t + 256];
    float mu = block_sum256(v0 + v1, red) * (1.0f / D);
    float d0 = v0 - mu, d1 = v1 - mu;
    float var = block_sum256(d0 * d0 + d1 * d1, red) * (1.0f / D);
    float rstd = rsqrtf(var + EPS_LN);
    out[(size_t)row * D + t]       = d0 * rstd * gamma[t] + beta[t];
    out[(size_t)row * D + t + 256] = d1 * rstd * gamma[t + 256] + beta[t + 256];
}

// ---------------------------------------------------------------------------
// 128x128-tile bf16 MFMA GEMM, BK=64, fused QKV epilogue (N=1536):
// Q,K -> [bh][n][dh] + sumsq, V -> [bh][dh][n] via LDS transpose.
// 1D grid, by = id & 63 (XCD-local A reuse).
// ---------------------------------------------------------------------------
template <int MT>
__global__ __launch_bounds__(256) void gemm_qkv(const unsigned short* __restrict__ A,
                                                const unsigned short* __restrict__ Wt,
                                                const float* __restrict__ bias0,
                                                const float* __restrict__ bias1,
                                                const float* __restrict__ bias2,
                                                unsigned short* __restrict__ Qo,
                                                unsigned short* __restrict__ Ko,
                                                unsigned short* __restrict__ Vo,
                                                float* __restrict__ sq0,
                                                float* __restrict__ sq1) {
    constexpr int RB = M_ROWS / MT;
    constexpr int NI = MT / 32;
    constexpr int ASZ = MT * 64, BSZ = 128 * 64;
    constexpr int SMSZ = (ASZ + BSZ > 18432) ? ASZ + BSZ : 18432;
    __shared__ unsigned short smem[SMSZ];
    unsigned short* As = smem;
    unsigned short* Bs = smem + ASZ;

    const int id = blockIdx.x;
    const int by = id & (RB - 1), bx = id / RB;
    const int tid = threadIdx.x;
    const int lane = tid & 63, wv = tid >> 6;
    const int quad = lane >> 4, l15 = lane & 15;
    const int row0 = by * MT, col0 = bx * 128;
    const int wm = (wv & 1) * (MT / 2), wn = (wv >> 1) * 64;

    f32x4 acc[NI][4];
    #pragma unroll
    for (int i = 0; i < NI; ++i)
        #pragma unroll
        for (int j = 0; j < 4; ++j) acc[i][j] = (f32x4){0.f, 0.f, 0.f, 0.f};

    const unsigned short* Ag = A  + (size_t)row0 * 512;
    const unsigned short* Bg = Wt + (size_t)col0 * 512;

    for (int k0 = 0; k0 < 512; k0 += 64) {
        __syncthreads();
        #pragma unroll
        for (int c = 0; c < ASZ / 2048; ++c) {
            int fu = c * 2048 + tid * 8;
            int r = fu >> 6, ko = fu & 63;
            async_ld16(As + fu, Ag + (size_t)r * 512 + k0 + ko);
        }
        #pragma unroll
        for (int c = 0; c < BSZ / 2048; ++c) {
            int fu = c * 2048 + tid * 8;
            int r = fu >> 6, ko = fu & 63;
            async_ld16(Bs + fu, Bg + (size_t)r * 512 + k0 + ko);
        }
        __syncthreads();

        #pragma unroll
        for (int ks = 0; ks < 2; ++ks) {
            short8 af[NI], bf[4];
            #pragma unroll
            for (int i = 0; i < NI; ++i)
                af[i] = *(const short8*)&As[(wm + i * 16 + l15) * 64 + ks * 32 + quad * 8];
            #pragma unroll
            for (int j = 0; j < 4; ++j)
                bf[j] = *(const short8*)&Bs[(wn + j * 16 + l15) * 64 + ks * 32 + quad * 8];
            #pragma unroll
            for (int i = 0; i < NI; ++i)
                #pragma unroll
                for (int j = 0; j < 4; ++j)
                    acc[i][j] = __builtin_amdgcn_mfma_f32_16x16x32_bf16(af[i], bf[j], acc[i][j], 0, 0, 0);
        }
    }

    const int colg = col0 + wn;
    const int seg = colg >> 9;                 // 0=Q 1=K 2=V
    const int hh = (colg & 511) >> 6;
    const float* bias = seg == 0 ? bias0 : seg == 1 ? bias1 : bias2;

    if (seg < 2) {
        unsigned short* dst = seg == 0 ? Qo : Ko;
        float* sq = seg == 0 ? sq0 : sq1;
        #pragma unroll
        for (int i = 0; i < NI; ++i) {
            const int m0 = row0 + wm + i * 16 + quad * 4;
            float ss[4] = {0.f, 0.f, 0.f, 0.f};
            #pragma unroll
            for (int j = 0; j < 4; ++j) {
                float bvj = bias[hh * 64 + j * 16 + l15];
                #pragma unroll
                for (int r = 0; r < 4; ++r) {
                    float v = acc[i][j][r] + bvj;
                    unsigned short ub = bfbits(v);
                    float vr = bf2f(ub);
                    ss[r] += vr * vr;
                    int m = m0 + r;
                    int b_ = m >> 10, n_ = m & 1023;
                    dst[((size_t)((b_ * 8 + hh) * 1024) + n_) * 64 + j * 16 + l15] = ub;
                }
            }
            #pragma unroll
            for (int r = 0; r < 4; ++r) {
                float s = ss[r];
                s += __shfl_xor(s, 1, 64);
                s += __shfl_xor(s, 2, 64);
                s += __shfl_xor(s, 4, 64);
                s += __shfl_xor(s, 8, 64);
                if (l15 == 0) {
                    int m = m0 + r;
                    sq[(size_t)((m >> 10) * 8 + hh) * 1024 + (m & 1023)] = s;
                }
            }
        }
    } else {
        // V: transpose through per-wave LDS region, then coalesced stores
        __syncthreads();   // whole block is V (uniform): safe
        unsigned short* T = smem + wv * 4608;  // [64 d][72]
        #pragma unroll
        for (int i = 0; i < NI; ++i)
            #pragma unroll
            for (int j = 0; j < 4; ++j) {
                float bvj = bias[hh * 64 + j * 16 + l15];
                ushort4 pk;
                pk.x = bfbits(acc[i][j][0] + bvj);
                pk.y = bfbits(acc[i][j][1] + bvj);
                pk.z = bfbits(acc[i][j][2] + bvj);
                pk.w = bfbits(acc[i][j][3] + bvj);
                *(ushort4*)&T[(j * 16 + l15) * 72 + i * 16 + quad * 4] = pk;
            }
        const int b_ = (row0 + wm) >> 10;
        const int nbase = (row0 + wm) & 1023;
        unsigned short* Vg = Vo + ((size_t)((b_ * 8 + hh) * 64)) * 1024 + nbase;
        #pragma unroll
        for (int it = 0; it < 8; ++it) {
            int dl = it * 8 + (lane >> 3);
            int nl = (lane & 7) * 8;
            uint4 v = *(const uint4*)&T[dl * 72 + nl];
            *(uint4*)&Vg[(size_t)dl * 1024 + nl] = v;
        }
    }
}

// ---------------------------------------------------------------------------
// Out-projection GEMM: Ob[M,512] @ WtO -> Y0 bf16. 64x128 tile, BK=64,
// 512 blocks (2/CU), by = id & 127 for XCD-local A reuse.
// ---------------------------------------------------------------------------
__global__ __launch_bounds__(256) void gemm_out(const unsigned short* __restrict__ A,
                                                const unsigned short* __restrict__ Wt,
                                                const float* __restrict__ bias,
                                                unsigned short* __restrict__ C) {
    __shared__ unsigned short As[64 * 64];
    __shared__ unsigned short Bs[128 * 64];

    const int id = blockIdx.x;
    const int by = id & 127, bx = id >> 7;
    const int tid = threadIdx.x;
    const int lane = tid & 63, wv = tid >> 6;
    const int quad = lane >> 4, l15 = lane & 15;
    const int row0 = by * 64, col0 = bx * 128;
    const int wm = (wv & 1) * 32, wn = (wv >> 1) * 64;

    f32x4 acc[2][4];
    #pragma unroll
    for (int i = 0; i < 2; ++i)
        #pragma unroll
        for (int j = 0; j < 4; ++j) acc[i][j] = (f32x4){0.f, 0.f, 0.f, 0.f};

    const unsigned short* Ag = A  + (size_t)row0 * 512;
    const unsigned short* Bg = Wt + (size_t)col0 * 512;

    for (int k0 = 0; k0 < 512; k0 += 64) {
        __syncthreads();
        #pragma unroll
        for (int c = 0; c < 2; ++c) {
            int fu = c * 2048 + tid * 8;
            int r = fu >> 6, ko = fu & 63;
            async_ld16(As + fu, Ag + (size_t)r * 512 + k0 + ko);
        }
        #pragma unroll
        for (int c = 0; c < 4; ++c) {
            int fu = c * 2048 + tid * 8;
            int r = fu >> 6, ko = fu & 63;
            async_ld16(Bs + fu, Bg + (size_t)r * 512 + k0 + ko);
        }
        __syncthreads();

        #pragma unroll
        for (int ks = 0; ks < 2; ++ks) {
            short8 af[2], bf[4];
            #pragma unroll
            for (int i = 0; i < 2; ++i)
                af[i] = *(const short8*)&As[(wm + i * 16 + l15) * 64 + ks * 32 + quad * 8];
            #pragma unroll
            for (int j = 0; j < 4; ++j)
                bf[j] = *(const short8*)&Bs[(wn + j * 16 + l15) * 64 + ks * 32 + quad * 8];
            #pragma unroll
            for (int i = 0; i < 2; ++i)
                #pragma unroll
                for (int j = 0; j < 4; ++j)
                    acc[i][j] = __builtin_amdgcn_mfma_f32_16x16x32_bf16(af[i], bf[j], acc[i][j], 0, 0, 0);
        }
    }

    #pragma unroll
    for (int i = 0; i < 2; ++i)
        #pragma unroll
        for (int j = 0; j < 4; ++j) {
            int col = col0 + wn + j * 16 + l15;
            float bv = bias[col];
            #pragma unroll
            for (int r = 0; r < 4; ++r) {
                int row = row0 + wm + i * 16 + quad * 4 + r;
                C[(size_t)row * 512 + col] = bfbits(acc[i][j][r] + bv);
            }
        }
}

// ---------------------------------------------------------------------------
// MFMA distance attention. Block = 8 waves (512 thr), 128 q rows (16 q/wave)
// per (b,h). V pre-transposed [bh][dh][n]. Double-buffered K/V + register
// prefetch. LDS: stride-64 rows + XOR swizzle -> zero bank conflicts.
// bh = id & 63 -> same-head blocks share an XCD.
// ---------------------------------------------------------------------------
__global__ __launch_bounds__(512) void attn_kernel(const unsigned short* __restrict__ Q,
                                                   const unsigned short* __restrict__ K,
                                                   const unsigned short* __restrict__ Vt,
                                                   const float* __restrict__ qsq,
                                                   const float* __restrict__ ksq,
                                                   unsigned short* __restrict__ O) {
    __shared__ unsigned short Ks[2][64 * 64];
    __shared__ unsigned short Vs[2][64 * 64];
    __shared__ unsigned short Ps[8][16 * 64];
    __shared__ float ksq_s[2][64];

    const int id = blockIdx.x;
    const int bh = id & 63, qb = id >> 6;
    const int q0 = qb * 128;
    const int tid = threadIdx.x;
    const int lane = tid & 63, w = tid >> 6;
    const int quad = lane >> 4, l15 = lane & 15;
    const int b_ = bh >> 3, h_ = bh & 7;

    const unsigned short* Qb = Q  + (size_t)bh * N * DH;
    const unsigned short* Kb = K  + (size_t)bh * N * DH;
    const unsigned short* Vb = Vt + (size_t)bh * DH * N;

    short8 qf0, qf1;
    {
        const unsigned short* qp = Qb + (size_t)(q0 + w * 16 + l15) * 64 + quad * 8;
        qf0 = *(const short8*)qp;
        qf1 = *(const short8*)(qp + 32);
    }
    float qe[4];
    #pragma unroll
    for (int r = 0; r < 4; ++r)
        qe[r] = qsq[bh * N + q0 + w * 16 + quad * 4 + r] + EPS_DIST;

    f32x4 oacc[4];
    #pragma unroll
    for (int dt = 0; dt < 4; ++dt) oacc[dt] = (f32x4){0.f, 0.f, 0.f, 0.f};
    float dpart[4] = {};

    // staging: 512 threads, 16B each; swizzled destination column
    const int rr = tid >> 3;
    const int scol = ((tid & 7) * 8) ^ swz(rr);
    uint4 kreg, vreg;
    float ksreg = 0.f;

    kreg = *(const uint4*)(Kb + (size_t)rr * 64 + (tid & 7) * 8);
    vreg = *(const uint4*)(Vb + (size_t)rr * N + (tid & 7) * 8);
    if (tid < 64) ksreg = ksq[bh * N + tid];

    *(uint4*)&Ks[0][rr * 64 + scol] = kreg;
    *(uint4*)&Vs[0][rr * 64 + scol] = vreg;
    if (tid < 64) ksq_s[0][tid] = ksreg;
    __syncthreads();

    // per-lane read swizzles (row bits 0..3 only -> same for row and row+16k)
    const int sR = swz(l15);

    #pragma unroll 2
    for (int kt = 0; kt < 16; ++kt) {
        const int cur = kt & 1;
        if (kt < 15) {
            kreg = *(const uint4*)(Kb + (size_t)((kt + 1) * 64 + rr) * 64 + (tid & 7) * 8);
            vreg = *(const uint4*)(Vb + (size_t)rr * N + (kt + 1) * 64 + (tid & 7) * 8);
            if (tid < 64) ksreg = ksq[bh * N + (kt + 1) * 64 + tid];
        }

        // scores + transform -> Ps  (16 q x 64 keys per wave)
        #pragma unroll
        for (int kb = 0; kb < 4; ++kb) {
            const int krow = kb * 16 + l15;
            short8 kf0 = *(const short8*)&Ks[cur][krow * 64 + ((quad * 8) ^ sR)];
            short8 kf1 = *(const short8*)&Ks[cur][krow * 64 + ((32 + quad * 8) ^ sR)];
            float ks2 = ksq_s[cur][kb * 16 + l15];
            f32x4 sa = (f32x4){0.f, 0.f, 0.f, 0.f};
            sa = __builtin_amdgcn_mfma_f32_16x16x32_bf16(qf0, kf0, sa, 0, 0, 0);
            sa = __builtin_amdgcn_mfma_f32_16x16x32_bf16(qf1, kf1, sa, 0, 0, 0);
            #pragma unroll
            for (int r = 0; r < 4; ++r) {
                float d2 = fmaf(-2.0f, sa[r], qe[r] + ks2);
                d2 = fmaxf(d2, EPS_DIST);
                float p = __expf(-__builtin_amdgcn_sqrtf(d2));
                dpart[r] += p;
                union { float f; unsigned u; } pu; pu.f = p;
                const int prow = quad * 4 + r;
                Ps[w][prow * 64 + ((kb * 16 + l15) ^ swz(prow))] =
                    (unsigned short)(pu.u >> 16);
            }
        }

        // PV
        short8 vf[4][2];
        #pragma unroll
        for (int dt = 0; dt < 4; ++dt) {
            const int vrow = dt * 16 + l15;
            #pragma unroll
            for (int kc = 0; kc < 2; ++kc)
                vf[dt][kc] = *(const short8*)&Vs[cur][vrow * 64 + ((kc * 32 + quad * 8) ^ sR)];
        }
        #pragma unroll
        for (int kc = 0; kc < 2; ++kc) {
            short8 pf = *(const short8*)&Ps[w][l15 * 64 + ((kc * 32 + quad * 8) ^ sR)];
            #pragma unroll
            for (int dt = 0; dt < 4; ++dt)
                oacc[dt] = __builtin_amdgcn_mfma_f32_16x16x32_bf16(pf, vf[dt][kc], oacc[dt], 0, 0, 0);
        }

        if (kt < 15) {
            *(uint4*)&Ks[cur ^ 1][rr * 64 + scol] = kreg;
            *(uint4*)&Vs[cur ^ 1][rr * 64 + scol] = vreg;
            if (tid < 64) ksq_s[cur ^ 1][tid] = ksreg;
        }
        __syncthreads();
    }

    float rinv[4];
    #pragma unroll
    for (int r = 0; r < 4; ++r) {
        float s = dpart[r];
        s += __shfl_xor(s, 1, 64);
        s += __shfl_xor(s, 2, 64);
        s += __shfl_xor(s, 4, 64);
        s += __shfl_xor(s, 8, 64);
        rinv[r] = 1.0f / s;
    }

    #pragma unroll
    for (int dt = 0; dt < 4; ++dt)
        #pragma unroll
        for (int r = 0; r < 4; ++r) {
            int n_ = q0 + w * 16 + quad * 4 + r;
            O[((size_t)(b_ * N + n_) * D) + h_ * DH + dt * 16 + l15] =
                bfbits(oacc[dt][r] * rinv[r]);
        }
}

// ---------------------------------------------------------------------------
extern "C" void kernel_launch(void* const* d_in, const int* in_sizes, int n_in,
                              void* d_out, int out_size, void* d_ws, size_t ws_size,
                              hipStream_t stream) {
    const float* x     = (const float*)d_in[0];
    const float* Wq    = (const float*)d_in[1];
    const float* Wk    = (const float*)d_in[2];
    const float* Wv    = (const float*)d_in[3];
    const float* Wo    = (const float*)d_in[4];
    const float* bq    = (const float*)d_in[5];
    const float* bk    = (const float*)d_in[6];
    const float* bv    = (const float*)d_in[7];
    const float* bo    = (const float*)d_in[8];
    const float* ln1_g = (const float*)d_in[9];
    const float* ln1_b = (const float*)d_in[10];
    const float* ln2_g = (const float*)d_in[11];
    const float* ln2_b = (const float*)d_in[12];
    float* out = (float*)d_out;

    unsigned short* WtAll = (unsigned short*)d_ws;    // [4][512][512] bf16
    unsigned short* h_bf  = WtAll + 4 * 262144;       // [8192][512]
    unsigned short* Qb    = h_bf + 4194304;           // [64][1024][64]
    unsigned short* Kb    = Qb + 4194304;
    unsigned short* Vtg   = Kb + 4194304;             // [64][64][1024] transposed
    unsigned short* Ob    = Vtg + 4194304;            // [8192][512]
    unsigned short* Y0    = Ob + 4194304;             // [8192][512] bf16
    float* qsq = (float*)(Y0 + 4194304);              // [65536]
    float* ksq = qsq + 65536;

    // 1) weights -> bf16^T  +  LN1 -> bf16 (fused launch)
    prep_kernel<<<256 + M_ROWS, 256, 0, stream>>>(Wq, Wk, Wv, Wo, WtAll,
                                                  x, ln1_g, ln1_b, h_bf);

    // 2) fused QKV projection (N=1536) + scatter + sum-squares
    gemm_qkv<128><<<768, 256, 0, stream>>>(h_bf, WtAll, bq, bk, bv,
                                           Qb, Kb, Vtg, qsq, ksq);

    // 3) MFMA distance attention -> Ob [B,N,D] bf16
    attn_kernel<<<512, 512, 0, stream>>>(Qb, Kb, Vtg, qsq, ksq, Ob);

    // 4) output projection -> bf16 Y0
    gemm_out<<<512, 256, 0, stream>>>(Ob, WtAll + 3 * 262144, bo, Y0);

    // 5) residual + post-norm
    ln2_kernel<<<M_ROWS, 256, 0, stream>>>(Y0, x, ln2_g, ln2_b, out);
}

// Round 8
// 186.858 us; speedup vs baseline: 1.0241x; 1.0093x over previous
//
#include <hip/hip_runtime.h>
#include <math.h>

typedef __attribute__((ext_vector_type(8))) short short8;   // 8 x bf16 (4 VGPRs)
typedef __attribute__((ext_vector_type(4))) float f32x4;    // MFMA acc

constexpr int B  = 8;
constexpr int N  = 1024;
constexpr int D  = 512;
constexpr int H  = 8;
constexpr int DH = 64;
constexpr int M_ROWS = 8192;
constexpr float EPS_DIST = 1e-8f;
constexpr float EPS_LN   = 1e-5f;

// fp32 -> bf16 bits (RNE)
__device__ inline unsigned short bfbits(float f) {
    union { float f; unsigned u; } v; v.f = f;
    unsigned r = v.u + 0x7fffu + ((v.u >> 16) & 1u);
    return (unsigned short)(r >> 16);
}
__device__ inline float bf2f(unsigned short s) {
    union { unsigned u; float f; } v; v.u = ((unsigned)s) << 16; return v.f;
}

// async 16B global->LDS (per lane; LDS dest = wave-uniform base + lane*16)
__device__ inline void async_ld16(unsigned short* lds, const unsigned short* g) {
    __builtin_amdgcn_global_load_lds(
        (const __attribute__((address_space(1))) unsigned int*)(g),
        (__attribute__((address_space(3))) unsigned int*)(lds),
        16, 0, 0);
}

__device__ inline float block_sum256(float s, float* red) {
    for (int o = 32; o > 0; o >>= 1) s += __shfl_down(s, o, 64);
    int lane = threadIdx.x & 63, wid = threadIdx.x >> 6;
    if (lane == 0) red[wid] = s;
    __syncthreads();
    if (threadIdx.x == 0) red[4] = red[0] + red[1] + red[2] + red[3];
    __syncthreads();
    return red[4];
}

// ---------------------------------------------------------------------------
// Fused: blocks 0..255 transpose+convert the 4 weights to bf16;
// blocks 256..8447 do LN1 (x -> h bf16).
// ---------------------------------------------------------------------------
__global__ __launch_bounds__(256) void prep_kernel(const float* __restrict__ Wq,
                                                   const float* __restrict__ Wk,
                                                   const float* __restrict__ Wv,
                                                   const float* __restrict__ Wo,
                                                   unsigned short* __restrict__ WtAll,
                                                   const float* __restrict__ x,
                                                   const float* __restrict__ ln1_g,
                                                   const float* __restrict__ ln1_b,
                                                   unsigned short* __restrict__ h_bf) {
    __shared__ float red[8];
    const int bxg = blockIdx.x;
    if (bxg < 256) {
        int sub = bxg >> 6;
        const float* W = sub == 0 ? Wq : sub == 1 ? Wk : sub == 2 ? Wv : Wo;
        unsigned short* Wt = WtAll + (size_t)sub * 262144;
        int t = (bxg & 63) * 256 + threadIdx.x;
        int tn = t & 127, tk = t >> 7;
        int k = tk * 4, n = tn * 4;
        float4 r0 = *(const float4*)&W[(size_t)(k + 0) * 512 + n];
        float4 r1 = *(const float4*)&W[(size_t)(k + 1) * 512 + n];
        float4 r2 = *(const float4*)&W[(size_t)(k + 2) * 512 + n];
        float4 r3 = *(const float4*)&W[(size_t)(k + 3) * 512 + n];
        ushort4 c;
        c.x = bfbits(r0.x); c.y = bfbits(r1.x); c.z = bfbits(r2.x); c.w = bfbits(r3.x);
        *(ushort4*)&Wt[(size_t)(n + 0) * 512 + k] = c;
        c.x = bfbits(r0.y); c.y = bfbits(r1.y); c.z = bfbits(r2.y); c.w = bfbits(r3.y);
        *(ushort4*)&Wt[(size_t)(n + 1) * 512 + k] = c;
        c.x = bfbits(r0.z); c.y = bfbits(r1.z); c.z = bfbits(r2.z); c.w = bfbits(r3.z);
        *(ushort4*)&Wt[(size_t)(n + 2) * 512 + k] = c;
        c.x = bfbits(r0.w); c.y = bfbits(r1.w); c.z = bfbits(r2.w); c.w = bfbits(r3.w);
        *(ushort4*)&Wt[(size_t)(n + 3) * 512 + k] = c;
    } else {
        const int row = bxg - 256;
        const int t = threadIdx.x;
        const float* xr = x + (size_t)row * D;
        float v0 = xr[t], v1 = xr[t + 256];
        float mu = block_sum256(v0 + v1, red) * (1.0f / D);
        float d0 = v0 - mu, d1 = v1 - mu;
        float var = block_sum256(d0 * d0 + d1 * d1, red) * (1.0f / D);
        float rstd = rsqrtf(var + EPS_LN);
        h_bf[(size_t)row * D + t]       = bfbits(d0 * rstd * ln1_g[t] + ln1_b[t]);
        h_bf[(size_t)row * D + t + 256] = bfbits(d1 * rstd * ln1_g[t + 256] + ln1_b[t + 256]);
    }
}

// ---------------------------------------------------------------------------
// LN2: y = LN(bf16 Y0 + fp32 x) -> fp32 out
// ---------------------------------------------------------------------------
__global__ __launch_bounds__(256) void ln2_kernel(const unsigned short* __restrict__ y0,
                                                  const float* __restrict__ res,
                                                  const float* __restrict__ gamma,
                                                  const float* __restrict__ beta,
                                                  float* __restrict__ out) {
    __shared__ float red[8];
    const int row = blockIdx.x;
    const int t = threadIdx.x;
    const unsigned short* xr = y0 + (size_t)row * D;
    const float* rr = res + (size_t)row * D;
    float v0 = bf2f(xr[t]) + rr[t];
    float v1 = bf2f(xr[t + 256]) + rr[t + 256];
    float mu = block_sum256(v0 + v1, red) * (1.0f / D);
    float d0 = v0 - mu, d1 = v1 - mu;
    float var = block_sum256(d0 * d0 + d1 * d1, red) * (1.0f / D);
    float rstd = rsqrtf(var + EPS_LN);
    out[(size_t)row * D + t]       = d0 * rstd * gamma[t] + beta[t];
    out[(size_t)row * D + t + 256] = d1 * rstd * gamma[t + 256] + beta[t + 256];
}

// ---------------------------------------------------------------------------
// 128x128-tile bf16 MFMA GEMM, BK=64, fused QKV epilogue (N=1536):
// Q,K -> [bh][n][dh] + sumsq, V -> [bh][dh][n] via LDS transpose.
// 1D grid, by = id & 63 (XCD-local A reuse).
// ---------------------------------------------------------------------------
template <int MT>
__global__ __launch_bounds__(256) void gemm_qkv(const unsigned short* __restrict__ A,
                                                const unsigned short* __restrict__ Wt,
                                                const float* __restrict__ bias0,
                                                const float* __restrict__ bias1,
                                                const float* __restrict__ bias2,
                                                unsigned short* __restrict__ Qo,
                                                unsigned short* __restrict__ Ko,
                                                unsigned short* __restrict__ Vo,
                                                float* __restrict__ sq0,
                                                float* __restrict__ sq1) {
    constexpr int RB = M_ROWS / MT;
    constexpr int NI = MT / 32;
    constexpr int ASZ = MT * 64, BSZ = 128 * 64;
    constexpr int SMSZ = (ASZ + BSZ > 18432) ? ASZ + BSZ : 18432;
    __shared__ unsigned short smem[SMSZ];
    unsigned short* As = smem;
    unsigned short* Bs = smem + ASZ;

    const int id = blockIdx.x;
    const int by = id & (RB - 1), bx = id / RB;
    const int tid = threadIdx.x;
    const int lane = tid & 63, wv = tid >> 6;
    const int quad = lane >> 4, l15 = lane & 15;
    const int row0 = by * MT, col0 = bx * 128;
    const int wm = (wv & 1) * (MT / 2), wn = (wv >> 1) * 64;

    f32x4 acc[NI][4];
    #pragma unroll
    for (int i = 0; i < NI; ++i)
        #pragma unroll
        for (int j = 0; j < 4; ++j) acc[i][j] = (f32x4){0.f, 0.f, 0.f, 0.f};

    const unsigned short* Ag = A  + (size_t)row0 * 512;
    const unsigned short* Bg = Wt + (size_t)col0 * 512;

    for (int k0 = 0; k0 < 512; k0 += 64) {
        __syncthreads();
        #pragma unroll
        for (int c = 0; c < ASZ / 2048; ++c) {
            int fu = c * 2048 + tid * 8;
            int r = fu >> 6, ko = fu & 63;
            async_ld16(As + fu, Ag + (size_t)r * 512 + k0 + ko);
        }
        #pragma unroll
        for (int c = 0; c < BSZ / 2048; ++c) {
            int fu = c * 2048 + tid * 8;
            int r = fu >> 6, ko = fu & 63;
            async_ld16(Bs + fu, Bg + (size_t)r * 512 + k0 + ko);
        }
        __syncthreads();

        #pragma unroll
        for (int ks = 0; ks < 2; ++ks) {
            short8 af[NI], bf[4];
            #pragma unroll
            for (int i = 0; i < NI; ++i)
                af[i] = *(const short8*)&As[(wm + i * 16 + l15) * 64 + ks * 32 + quad * 8];
            #pragma unroll
            for (int j = 0; j < 4; ++j)
                bf[j] = *(const short8*)&Bs[(wn + j * 16 + l15) * 64 + ks * 32 + quad * 8];
            #pragma unroll
            for (int i = 0; i < NI; ++i)
                #pragma unroll
                for (int j = 0; j < 4; ++j)
                    acc[i][j] = __builtin_amdgcn_mfma_f32_16x16x32_bf16(af[i], bf[j], acc[i][j], 0, 0, 0);
        }
    }

    const int colg = col0 + wn;
    const int seg = colg >> 9;                 // 0=Q 1=K 2=V
    const int hh = (colg & 511) >> 6;
    const float* bias = seg == 0 ? bias0 : seg == 1 ? bias1 : bias2;

    if (seg < 2) {
        unsigned short* dst = seg == 0 ? Qo : Ko;
        float* sq = seg == 0 ? sq0 : sq1;
        #pragma unroll
        for (int i = 0; i < NI; ++i) {
            const int m0 = row0 + wm + i * 16 + quad * 4;
            float ss[4] = {0.f, 0.f, 0.f, 0.f};
            #pragma unroll
            for (int j = 0; j < 4; ++j) {
                float bvj = bias[hh * 64 + j * 16 + l15];
                #pragma unroll
                for (int r = 0; r < 4; ++r) {
                    float v = acc[i][j][r] + bvj;
                    unsigned short ub = bfbits(v);
                    float vr = bf2f(ub);
                    ss[r] += vr * vr;
                    int m = m0 + r;
                    int b_ = m >> 10, n_ = m & 1023;
                    dst[((size_t)((b_ * 8 + hh) * 1024) + n_) * 64 + j * 16 + l15] = ub;
                }
            }
            #pragma unroll
            for (int r = 0; r < 4; ++r) {
                float s = ss[r];
                s += __shfl_xor(s, 1, 64);
                s += __shfl_xor(s, 2, 64);
                s += __shfl_xor(s, 4, 64);
                s += __shfl_xor(s, 8, 64);
                if (l15 == 0) {
                    int m = m0 + r;
                    sq[(size_t)((m >> 10) * 8 + hh) * 1024 + (m & 1023)] = s;
                }
            }
        }
    } else {
        // V: transpose through per-wave LDS region, then coalesced stores
        __syncthreads();   // whole block is V (uniform): safe
        unsigned short* T = smem + wv * 4608;  // [64 d][72]
        #pragma unroll
        for (int i = 0; i < NI; ++i)
            #pragma unroll
            for (int j = 0; j < 4; ++j) {
                float bvj = bias[hh * 64 + j * 16 + l15];
                ushort4 pk;
                pk.x = bfbits(acc[i][j][0] + bvj);
                pk.y = bfbits(acc[i][j][1] + bvj);
                pk.z = bfbits(acc[i][j][2] + bvj);
                pk.w = bfbits(acc[i][j][3] + bvj);
                *(ushort4*)&T[(j * 16 + l15) * 72 + i * 16 + quad * 4] = pk;
            }
        const int b_ = (row0 + wm) >> 10;
        const int nbase = (row0 + wm) & 1023;
        unsigned short* Vg = Vo + ((size_t)((b_ * 8 + hh) * 64)) * 1024 + nbase;
        #pragma unroll
        for (int it = 0; it < 8; ++it) {
            int dl = it * 8 + (lane >> 3);
            int nl = (lane & 7) * 8;
            uint4 v = *(const uint4*)&T[dl * 72 + nl];
            *(uint4*)&Vg[(size_t)dl * 1024 + nl] = v;
        }
    }
}

// ---------------------------------------------------------------------------
// Out-projection GEMM: Ob[M,512] @ WtO -> Y0 bf16. 64x128 tile, BK=64,
// 512 blocks (2/CU), by = id & 127 for XCD-local A reuse.
// ---------------------------------------------------------------------------
__global__ __launch_bounds__(256) void gemm_out(const unsigned short* __restrict__ A,
                                                const unsigned short* __restrict__ Wt,
                                                const float* __restrict__ bias,
                                                unsigned short* __restrict__ C) {
    __shared__ unsigned short As[64 * 64];
    __shared__ unsigned short Bs[128 * 64];

    const int id = blockIdx.x;
    const int by = id & 127, bx = id >> 7;
    const int tid = threadIdx.x;
    const int lane = tid & 63, wv = tid >> 6;
    const int quad = lane >> 4, l15 = lane & 15;
    const int row0 = by * 64, col0 = bx * 128;
    const int wm = (wv & 1) * 32, wn = (wv >> 1) * 64;

    f32x4 acc[2][4];
    #pragma unroll
    for (int i = 0; i < 2; ++i)
        #pragma unroll
        for (int j = 0; j < 4; ++j) acc[i][j] = (f32x4){0.f, 0.f, 0.f, 0.f};

    const unsigned short* Ag = A  + (size_t)row0 * 512;
    const unsigned short* Bg = Wt + (size_t)col0 * 512;

    for (int k0 = 0; k0 < 512; k0 += 64) {
        __syncthreads();
        #pragma unroll
        for (int c = 0; c < 2; ++c) {
            int fu = c * 2048 + tid * 8;
            int r = fu >> 6, ko = fu & 63;
            async_ld16(As + fu, Ag + (size_t)r * 512 + k0 + ko);
        }
        #pragma unroll
        for (int c = 0; c < 4; ++c) {
            int fu = c * 2048 + tid * 8;
            int r = fu >> 6, ko = fu & 63;
            async_ld16(Bs + fu, Bg + (size_t)r * 512 + k0 + ko);
        }
        __syncthreads();

        #pragma unroll
        for (int ks = 0; ks < 2; ++ks) {
            short8 af[2], bf[4];
            #pragma unroll
            for (int i = 0; i < 2; ++i)
                af[i] = *(const short8*)&As[(wm + i * 16 + l15) * 64 + ks * 32 + quad * 8];
            #pragma unroll
            for (int j = 0; j < 4; ++j)
                bf[j] = *(const short8*)&Bs[(wn + j * 16 + l15) * 64 + ks * 32 + quad * 8];
            #pragma unroll
            for (int i = 0; i < 2; ++i)
                #pragma unroll
                for (int j = 0; j < 4; ++j)
                    acc[i][j] = __builtin_amdgcn_mfma_f32_16x16x32_bf16(af[i], bf[j], acc[i][j], 0, 0, 0);
        }
    }

    #pragma unroll
    for (int i = 0; i < 2; ++i)
        #pragma unroll
        for (int j = 0; j < 4; ++j) {
            int col = col0 + wn + j * 16 + l15;
            float bv = bias[col];
            #pragma unroll
            for (int r = 0; r < 4; ++r) {
                int row = row0 + wm + i * 16 + quad * 4 + r;
                C[(size_t)row * 512 + col] = bfbits(acc[i][j][r] + bv);
            }
        }
}

// ---------------------------------------------------------------------------
// MFMA distance attention. Block = 4 waves (256 thr), 64 q rows (16 q/wave)
// per (b,h). 1024 blocks -> 4 blocks/CU resident (LDS 27.9 KB): cross-block
// overlap hides the per-block stage->compute chain. Single-buffered K/V +
// register prefetch (global latency hidden before barrier 1).
// bh = id & 63 -> same-head blocks share an XCD.
// ---------------------------------------------------------------------------
__global__ __launch_bounds__(256) void attn_kernel(const unsigned short* __restrict__ Q,
                                                   const unsigned short* __restrict__ K,
                                                   const unsigned short* __restrict__ Vt,
                                                   const float* __restrict__ qsq,
                                                   const float* __restrict__ ksq,
                                                   unsigned short* __restrict__ O) {
    __shared__ unsigned short Ks[64][72];
    __shared__ unsigned short Vs[64][72];
    __shared__ unsigned short Ps[4][16][72];
    __shared__ float ksq_s[64];

    const int id = blockIdx.x;
    const int bh = id & 63, qb = id >> 6;     // qb 0..15
    const int q0 = qb * 64;
    const int tid = threadIdx.x;
    const int lane = tid & 63, w = tid >> 6;
    const int quad = lane >> 4, l15 = lane & 15;
    const int b_ = bh >> 3, h_ = bh & 7;

    const unsigned short* Qb = Q  + (size_t)bh * N * DH;
    const unsigned short* Kb = K  + (size_t)bh * N * DH;
    const unsigned short* Vb = Vt + (size_t)bh * DH * N;

    short8 qf0, qf1;
    {
        const unsigned short* qp = Qb + (size_t)(q0 + w * 16 + l15) * 64 + quad * 8;
        qf0 = *(const short8*)qp;
        qf1 = *(const short8*)(qp + 32);
    }
    float qe[4];
    #pragma unroll
    for (int r = 0; r < 4; ++r)
        qe[r] = qsq[bh * N + q0 + w * 16 + quad * 4 + r] + EPS_DIST;

    f32x4 oacc[4];
    #pragma unroll
    for (int dt = 0; dt < 4; ++dt) oacc[dt] = (f32x4){0.f, 0.f, 0.f, 0.f};
    float dpart[4] = {};

    // staging: 256 threads, 2 x 16B each for K and V
    const int rr = tid >> 2, cc = (tid & 3) * 16;
    uint4 kreg0, kreg1, vreg0, vreg1;
    float ksreg = 0.f;

    kreg0 = *(const uint4*)(Kb + (size_t)rr * 64 + cc);
    kreg1 = *(const uint4*)(Kb + (size_t)rr * 64 + cc + 8);
    vreg0 = *(const uint4*)(Vb + (size_t)rr * N + cc);
    vreg1 = *(const uint4*)(Vb + (size_t)rr * N + cc + 8);
    if (tid < 64) ksreg = ksq[bh * N + tid];

    *(uint4*)&Ks[rr][cc]     = kreg0;
    *(uint4*)&Ks[rr][cc + 8] = kreg1;
    *(uint4*)&Vs[rr][cc]     = vreg0;
    *(uint4*)&Vs[rr][cc + 8] = vreg1;
    if (tid < 64) ksq_s[tid] = ksreg;
    __syncthreads();

    for (int kt = 0; kt < 16; ++kt) {
        if (kt < 15) {   // prefetch next tile into registers (hidden by compute)
            kreg0 = *(const uint4*)(Kb + (size_t)((kt + 1) * 64 + rr) * 64 + cc);
            kreg1 = *(const uint4*)(Kb + (size_t)((kt + 1) * 64 + rr) * 64 + cc + 8);
            vreg0 = *(const uint4*)(Vb + (size_t)rr * N + (kt + 1) * 64 + cc);
            vreg1 = *(const uint4*)(Vb + (size_t)rr * N + (kt + 1) * 64 + cc + 8);
            if (tid < 64) ksreg = ksq[bh * N + (kt + 1) * 64 + tid];
        }

        // scores + transform -> Ps  (16 q x 64 keys per wave)
        #pragma unroll
        for (int kb = 0; kb < 4; ++kb) {
            short8 kf0 = *(const short8*)&Ks[kb * 16 + l15][quad * 8];
            short8 kf1 = *(const short8*)&Ks[kb * 16 + l15][32 + quad * 8];
            float ks2 = ksq_s[kb * 16 + l15];
            f32x4 sa = (f32x4){0.f, 0.f, 0.f, 0.f};
            sa = __builtin_amdgcn_mfma_f32_16x16x32_bf16(qf0, kf0, sa, 0, 0, 0);
            sa = __builtin_amdgcn_mfma_f32_16x16x32_bf16(qf1, kf1, sa, 0, 0, 0);
            #pragma unroll
            for (int r = 0; r < 4; ++r) {
                float d2 = fmaf(-2.0f, sa[r], qe[r] + ks2);
                d2 = fmaxf(d2, EPS_DIST);
                float p = __expf(-__builtin_amdgcn_sqrtf(d2));
                dpart[r] += p;
                union { float f; unsigned u; } pu; pu.f = p;
                Ps[w][quad * 4 + r][kb * 16 + l15] = (unsigned short)(pu.u >> 16);
            }
        }

        // PV
        short8 vf[4][2];
        #pragma unroll
        for (int dt = 0; dt < 4; ++dt)
            #pragma unroll
            for (int kc = 0; kc < 2; ++kc)
                vf[dt][kc] = *(const short8*)&Vs[dt * 16 + l15][kc * 32 + quad * 8];
        #pragma unroll
        for (int kc = 0; kc < 2; ++kc) {
            short8 pf = *(const short8*)&Ps[w][l15][kc * 32 + quad * 8];
            #pragma unroll
            for (int dt = 0; dt < 4; ++dt)
                oacc[dt] = __builtin_amdgcn_mfma_f32_16x16x32_bf16(pf, vf[dt][kc], oacc[dt], 0, 0, 0);
        }

        if (kt < 15) {
            __syncthreads();   // all waves done reading tile kt
            *(uint4*)&Ks[rr][cc]     = kreg0;
            *(uint4*)&Ks[rr][cc + 8] = kreg1;
            *(uint4*)&Vs[rr][cc]     = vreg0;
            *(uint4*)&Vs[rr][cc + 8] = vreg1;
            if (tid < 64) ksq_s[tid] = ksreg;
            __syncthreads();   // writes visible
        }
    }

    float rinv[4];
    #pragma unroll
    for (int r = 0; r < 4; ++r) {
        float s = dpart[r];
        s += __shfl_xor(s, 1, 64);
        s += __shfl_xor(s, 2, 64);
        s += __shfl_xor(s, 4, 64);
        s += __shfl_xor(s, 8, 64);
        rinv[r] = 1.0f / s;
    }

    #pragma unroll
    for (int dt = 0; dt < 4; ++dt)
        #pragma unroll
        for (int r = 0; r < 4; ++r) {
            int n_ = q0 + w * 16 + quad * 4 + r;
            O[((size_t)(b_ * N + n_) * D) + h_ * DH + dt * 16 + l15] =
                bfbits(oacc[dt][r] * rinv[r]);
        }
}

// ---------------------------------------------------------------------------
extern "C" void kernel_launch(void* const* d_in, const int* in_sizes, int n_in,
                              void* d_out, int out_size, void* d_ws, size_t ws_size,
                              hipStream_t stream) {
    const float* x     = (const float*)d_in[0];
    const float* Wq    = (const float*)d_in[1];
    const float* Wk    = (const float*)d_in[2];
    const float* Wv    = (const float*)d_in[3];
    const float* Wo    = (const float*)d_in[4];
    const float* bq    = (const float*)d_in[5];
    const float* bk    = (const float*)d_in[6];
    const float* bv    = (const float*)d_in[7];
    const float* bo    = (const float*)d_in[8];
    const float* ln1_g = (const float*)d_in[9];
    const float* ln1_b = (const float*)d_in[10];
    const float* ln2_g = (const float*)d_in[11];
    const float* ln2_b = (const float*)d_in[12];
    float* out = (float*)d_out;

    unsigned short* WtAll = (unsigned short*)d_ws;    // [4][512][512] bf16
    unsigned short* h_bf  = WtAll + 4 * 262144;       // [8192][512]
    unsigned short* Qb    = h_bf + 4194304;           // [64][1024][64]
    unsigned short* Kb    = Qb + 4194304;
    unsigned short* Vtg   = Kb + 4194304;             // [64][64][1024] transposed
    unsigned short* Ob    = Vtg + 4194304;            // [8192][512]
    unsigned short* Y0    = Ob + 4194304;             // [8192][512] bf16
    float* qsq = (float*)(Y0 + 4194304);              // [65536]
    float* ksq = qsq + 65536;

    // 1) weights -> bf16^T  +  LN1 -> bf16 (fused launch)
    prep_kernel<<<256 + M_ROWS, 256, 0, stream>>>(Wq, Wk, Wv, Wo, WtAll,
                                                  x, ln1_g, ln1_b, h_bf);

    // 2) fused QKV projection (N=1536) + scatter + sum-squares
    gemm_qkv<128><<<768, 256, 0, stream>>>(h_bf, WtAll, bq, bk, bv,
                                           Qb, Kb, Vtg, qsq, ksq);

    // 3) MFMA distance attention -> Ob [B,N,D] bf16 (1024 blocks, 4/CU)
    attn_kernel<<<1024, 256, 0, stream>>>(Qb, Kb, Vtg, qsq, ksq, Ob);

    // 4) output projection -> bf16 Y0
    gemm_out<<<512, 256, 0, stream>>>(Ob, WtAll + 3 * 262144, bo, Y0);

    // 5) residual + post-norm
    ln2_kernel<<<M_ROWS, 256, 0, stream>>>(Y0, x, ln2_g, ln2_b, out);
}

// Round 9
// 185.139 us; speedup vs baseline: 1.0336x; 1.0093x over previous
//
#include <hip/hip_runtime.h>
#include <math.h>

typedef __attribute__((ext_vector_type(8)))  short short8;   // 8 x bf16 (4 VGPRs)
typedef __attribute__((ext_vector_type(4)))  float f32x4;    // 16x16 MFMA acc
typedef __attribute__((ext_vector_type(16))) float f32x16;   // 32x32 MFMA acc

constexpr int B  = 8;
constexpr int N  = 1024;
constexpr int D  = 512;
constexpr int H  = 8;
constexpr int DH = 64;
constexpr int M_ROWS = 8192;
constexpr float EPS_DIST = 1e-8f;
constexpr float EPS_LN   = 1e-5f;

// fp32 -> bf16 bits (RNE)
__device__ inline unsigned short bfbits(float f) {
    union { float f; unsigned u; } v; v.f = f;
    unsigned r = v.u + 0x7fffu + ((v.u >> 16) & 1u);
    return (unsigned short)(r >> 16);
}
__device__ inline float bf2f(unsigned short s) {
    union { unsigned u; float f; } v; v.u = ((unsigned)s) << 16; return v.f;
}

// async 16B global->LDS (per lane; LDS dest = wave-uniform base + lane*16)
__device__ inline void async_ld16(unsigned short* lds, const unsigned short* g) {
    __builtin_amdgcn_global_load_lds(
        (const __attribute__((address_space(1))) unsigned int*)(g),
        (__attribute__((address_space(3))) unsigned int*)(lds),
        16, 0, 0);
}

__device__ inline float block_sum256(float s, float* red) {
    for (int o = 32; o > 0; o >>= 1) s += __shfl_down(s, o, 64);
    int lane = threadIdx.x & 63, wid = threadIdx.x >> 6;
    if (lane == 0) red[wid] = s;
    __syncthreads();
    if (threadIdx.x == 0) red[4] = red[0] + red[1] + red[2] + red[3];
    __syncthreads();
    return red[4];
}

// ---------------------------------------------------------------------------
// Fused: blocks 0..255 transpose+convert the 4 weights to bf16;
// blocks 256..8447 do LN1 (x -> h bf16).
// ---------------------------------------------------------------------------
__global__ __launch_bounds__(256) void prep_kernel(const float* __restrict__ Wq,
                                                   const float* __restrict__ Wk,
                                                   const float* __restrict__ Wv,
                                                   const float* __restrict__ Wo,
                                                   unsigned short* __restrict__ WtAll,
                                                   const float* __restrict__ x,
                                                   const float* __restrict__ ln1_g,
                                                   const float* __restrict__ ln1_b,
                                                   unsigned short* __restrict__ h_bf) {
    __shared__ float red[8];
    const int bxg = blockIdx.x;
    if (bxg < 256) {
        int sub = bxg >> 6;
        const float* W = sub == 0 ? Wq : sub == 1 ? Wk : sub == 2 ? Wv : Wo;
        unsigned short* Wt = WtAll + (size_t)sub * 262144;
        int t = (bxg & 63) * 256 + threadIdx.x;
        int tn = t & 127, tk = t >> 7;
        int k = tk * 4, n = tn * 4;
        float4 r0 = *(const float4*)&W[(size_t)(k + 0) * 512 + n];
        float4 r1 = *(const float4*)&W[(size_t)(k + 1) * 512 + n];
        float4 r2 = *(const float4*)&W[(size_t)(k + 2) * 512 + n];
        float4 r3 = *(const float4*)&W[(size_t)(k + 3) * 512 + n];
        ushort4 c;
        c.x = bfbits(r0.x); c.y = bfbits(r1.x); c.z = bfbits(r2.x); c.w = bfbits(r3.x);
        *(ushort4*)&Wt[(size_t)(n + 0) * 512 + k] = c;
        c.x = bfbits(r0.y); c.y = bfbits(r1.y); c.z = bfbits(r2.y); c.w = bfbits(r3.y);
        *(ushort4*)&Wt[(size_t)(n + 1) * 512 + k] = c;
        c.x = bfbits(r0.z); c.y = bfbits(r1.z); c.z = bfbits(r2.z); c.w = bfbits(r3.z);
        *(ushort4*)&Wt[(size_t)(n + 2) * 512 + k] = c;
        c.x = bfbits(r0.w); c.y = bfbits(r1.w); c.z = bfbits(r2.w); c.w = bfbits(r3.w);
        *(ushort4*)&Wt[(size_t)(n + 3) * 512 + k] = c;
    } else {
        const int row = bxg - 256;
        const int t = threadIdx.x;
        const float* xr = x + (size_t)row * D;
        float v0 = xr[t], v1 = xr[t + 256];
        float mu = block_sum256(v0 + v1, red) * (1.0f / D);
        float d0 = v0 - mu, d1 = v1 - mu;
        float var = block_sum256(d0 * d0 + d1 * d1, red) * (1.0f / D);
        float rstd = rsqrtf(var + EPS_LN);
        h_bf[(size_t)row * D + t]       = bfbits(d0 * rstd * ln1_g[t] + ln1_b[t]);
        h_bf[(size_t)row * D + t + 256] = bfbits(d1 * rstd * ln1_g[t + 256] + ln1_b[t + 256]);
    }
}

// ---------------------------------------------------------------------------
// LN2: y = LN(bf16 Y0 + fp32 x) -> fp32 out
// ---------------------------------------------------------------------------
__global__ __launch_bounds__(256) void ln2_kernel(const unsigned short* __restrict__ y0,
                                                  const float* __restrict__ res,
                                                  const float* __restrict__ gamma,
                                                  const float* __restrict__ beta,
                                                  float* __restrict__ out) {
    __shared__ float red[8];
    const int row = blockIdx.x;
    const int t = threadIdx.x;
    const unsigned short* xr = y0 + (size_t)row * D;
    const float* rr = res + (size_t)row * D;
    float v0 = bf2f(xr[t]) + rr[t];
    float v1 = bf2f(xr[t + 256]) + rr[t + 256];
    float mu = block_sum256(v0 + v1, red) * (1.0f / D);
    float d0 = v0 - mu, d1 = v1 - mu;
    float var = block_sum256(d0 * d0 + d1 * d1, red) * (1.0f / D);
    float rstd = rsqrtf(var + EPS_LN);
    out[(size_t)row * D + t]       = d0 * rstd * gamma[t] + beta[t];
    out[(size_t)row * D + t + 256] = d1 * rstd * gamma[t + 256] + beta[t + 256];
}

// ---------------------------------------------------------------------------
// 128x128-tile bf16 MFMA GEMM, BK=64, fused QKV epilogue (N=1536):
// Q,K -> [bh][n][dh] + sumsq (coalesced via LDS transpose region),
// V -> [bh][dh][n] via LDS transpose. 1D grid, by = id & 63.
// ---------------------------------------------------------------------------
template <int MT>
__global__ __launch_bounds__(256) void gemm_qkv(const unsigned short* __restrict__ A,
                                                const unsigned short* __restrict__ Wt,
                                                const float* __restrict__ bias0,
                                                const float* __restrict__ bias1,
                                                const float* __restrict__ bias2,
                                                unsigned short* __restrict__ Qo,
                                                unsigned short* __restrict__ Ko,
                                                unsigned short* __restrict__ Vo,
                                                float* __restrict__ sq0,
                                                float* __restrict__ sq1) {
    constexpr int RB = M_ROWS / MT;
    constexpr int NI = MT / 32;
    constexpr int ASZ = MT * 64, BSZ = 128 * 64;
    constexpr int SMSZ = (ASZ + BSZ > 18432) ? ASZ + BSZ : 18432;
    __shared__ unsigned short smem[SMSZ];
    unsigned short* As = smem;
    unsigned short* Bs = smem + ASZ;

    const int id = blockIdx.x;
    const int by = id & (RB - 1), bx = id / RB;
    const int tid = threadIdx.x;
    const int lane = tid & 63, wv = tid >> 6;
    const int quad = lane >> 4, l15 = lane & 15;
    const int row0 = by * MT, col0 = bx * 128;
    const int wm = (wv & 1) * (MT / 2), wn = (wv >> 1) * 64;

    f32x4 acc[NI][4];
    #pragma unroll
    for (int i = 0; i < NI; ++i)
        #pragma unroll
        for (int j = 0; j < 4; ++j) acc[i][j] = (f32x4){0.f, 0.f, 0.f, 0.f};

    const unsigned short* Ag = A  + (size_t)row0 * 512;
    const unsigned short* Bg = Wt + (size_t)col0 * 512;

    for (int k0 = 0; k0 < 512; k0 += 64) {
        __syncthreads();
        #pragma unroll
        for (int c = 0; c < ASZ / 2048; ++c) {
            int fu = c * 2048 + tid * 8;
            int r = fu >> 6, ko = fu & 63;
            async_ld16(As + fu, Ag + (size_t)r * 512 + k0 + ko);
        }
        #pragma unroll
        for (int c = 0; c < BSZ / 2048; ++c) {
            int fu = c * 2048 + tid * 8;
            int r = fu >> 6, ko = fu & 63;
            async_ld16(Bs + fu, Bg + (size_t)r * 512 + k0 + ko);
        }
        __syncthreads();

        #pragma unroll
        for (int ks = 0; ks < 2; ++ks) {
            short8 af[NI], bf[4];
            #pragma unroll
            for (int i = 0; i < NI; ++i)
                af[i] = *(const short8*)&As[(wm + i * 16 + l15) * 64 + ks * 32 + quad * 8];
            #pragma unroll
            for (int j = 0; j < 4; ++j)
                bf[j] = *(const short8*)&Bs[(wn + j * 16 + l15) * 64 + ks * 32 + quad * 8];
            #pragma unroll
            for (int i = 0; i < NI; ++i)
                #pragma unroll
                for (int j = 0; j < 4; ++j)
                    acc[i][j] = __builtin_amdgcn_mfma_f32_16x16x32_bf16(af[i], bf[j], acc[i][j], 0, 0, 0);
        }
    }

    const int colg = col0 + wn;
    const int seg = colg >> 9;                 // 0=Q 1=K 2=V  (block-uniform)
    const int hh = (colg & 511) >> 6;
    const float* bias = seg == 0 ? bias0 : seg == 1 ? bias1 : bias2;

    __syncthreads();                           // done with As/Bs; reuse smem
    unsigned short* T = smem + wv * 4608;      // per-wave [64][72]
    const int b_ = (row0 + wm) >> 10;
    const int nbase = (row0 + wm) & 1023;

    if (seg < 2) {
        unsigned short* dst = seg == 0 ? Qo : Ko;
        float* sq = seg == 0 ? sq0 : sq1;
        #pragma unroll
        for (int i = 0; i < NI; ++i) {
            const int m0 = row0 + wm + i * 16 + quad * 4;
            float ss[4] = {0.f, 0.f, 0.f, 0.f};
            #pragma unroll
            for (int j = 0; j < 4; ++j) {
                float bvj = bias[hh * 64 + j * 16 + l15];
                #pragma unroll
                for (int r = 0; r < 4; ++r) {
                    float v = acc[i][j][r] + bvj;
                    unsigned short ub = bfbits(v);
                    float vr = bf2f(ub);
                    ss[r] += vr * vr;
                    T[(i * 16 + quad * 4 + r) * 72 + j * 16 + l15] = ub;
                }
            }
            #pragma unroll
            for (int r = 0; r < 4; ++r) {
                float s = ss[r];
                s += __shfl_xor(s, 1, 64);
                s += __shfl_xor(s, 2, 64);
                s += __shfl_xor(s, 4, 64);
                s += __shfl_xor(s, 8, 64);
                if (l15 == 0) {
                    int m = m0 + r;
                    sq[(size_t)((m >> 10) * 8 + hh) * 1024 + (m & 1023)] = s;
                }
            }
        }
        // coalesced store: [bh][n][dh], 8 consecutive n-rows (128B each) per instr
        unsigned short* dg = dst + ((size_t)((b_ * 8 + hh) * 1024) + nbase) * 64;
        #pragma unroll
        for (int it = 0; it < 8; ++it) {
            int rr2 = it * 8 + (lane >> 3);
            int cc2 = (lane & 7) * 8;
            *(uint4*)&dg[(size_t)rr2 * 64 + cc2] = *(const uint4*)&T[rr2 * 72 + cc2];
        }
    } else {
        // V: transpose through per-wave LDS region, then coalesced stores
        #pragma unroll
        for (int i = 0; i < NI; ++i)
            #pragma unroll
            for (int j = 0; j < 4; ++j) {
                float bvj = bias[hh * 64 + j * 16 + l15];
                ushort4 pk;
                pk.x = bfbits(acc[i][j][0] + bvj);
                pk.y = bfbits(acc[i][j][1] + bvj);
                pk.z = bfbits(acc[i][j][2] + bvj);
                pk.w = bfbits(acc[i][j][3] + bvj);
                *(ushort4*)&T[(j * 16 + l15) * 72 + i * 16 + quad * 4] = pk;
            }
        unsigned short* Vg = Vo + ((size_t)((b_ * 8 + hh) * 64)) * 1024 + nbase;
        #pragma unroll
        for (int it = 0; it < 8; ++it) {
            int dl = it * 8 + (lane >> 3);
            int nl = (lane & 7) * 8;
            uint4 v = *(const uint4*)&T[dl * 72 + nl];
            *(uint4*)&Vg[(size_t)dl * 1024 + nl] = v;
        }
    }
}

// ---------------------------------------------------------------------------
// Out-projection GEMM: Ob[M,512] @ WtO -> Y0 bf16. 64x128 tile, BK=64,
// coalesced epilogue via LDS. 512 blocks, by = id & 127.
// ---------------------------------------------------------------------------
__global__ __launch_bounds__(256) void gemm_out(const unsigned short* __restrict__ A,
                                                const unsigned short* __restrict__ Wt,
                                                const float* __restrict__ bias,
                                                unsigned short* __restrict__ C) {
    __shared__ unsigned short smem[64 * 64 + 128 * 64];
    unsigned short* As = smem;
    unsigned short* Bs = smem + 64 * 64;

    const int id = blockIdx.x;
    const int by = id & 127, bx = id >> 7;
    const int tid = threadIdx.x;
    const int lane = tid & 63, wv = tid >> 6;
    const int quad = lane >> 4, l15 = lane & 15;
    const int row0 = by * 64, col0 = bx * 128;
    const int wm = (wv & 1) * 32, wn = (wv >> 1) * 64;

    f32x4 acc[2][4];
    #pragma unroll
    for (int i = 0; i < 2; ++i)
        #pragma unroll
        for (int j = 0; j < 4; ++j) acc[i][j] = (f32x4){0.f, 0.f, 0.f, 0.f};

    const unsigned short* Ag = A  + (size_t)row0 * 512;
    const unsigned short* Bg = Wt + (size_t)col0 * 512;

    for (int k0 = 0; k0 < 512; k0 += 64) {
        __syncthreads();
        #pragma unroll
        for (int c = 0; c < 2; ++c) {
            int fu = c * 2048 + tid * 8;
            int r = fu >> 6, ko = fu & 63;
            async_ld16(As + fu, Ag + (size_t)r * 512 + k0 + ko);
        }
        #pragma unroll
        for (int c = 0; c < 4; ++c) {
            int fu = c * 2048 + tid * 8;
            int r = fu >> 6, ko = fu & 63;
            async_ld16(Bs + fu, Bg + (size_t)r * 512 + k0 + ko);
        }
        __syncthreads();

        #pragma unroll
        for (int ks = 0; ks < 2; ++ks) {
            short8 af[2], bf[4];
            #pragma unroll
            for (int i = 0; i < 2; ++i)
                af[i] = *(const short8*)&As[(wm + i * 16 + l15) * 64 + ks * 32 + quad * 8];
            #pragma unroll
            for (int j = 0; j < 4; ++j)
                bf[j] = *(const short8*)&Bs[(wn + j * 16 + l15) * 64 + ks * 32 + quad * 8];
            #pragma unroll
            for (int i = 0; i < 2; ++i)
                #pragma unroll
                for (int j = 0; j < 4; ++j)
                    acc[i][j] = __builtin_amdgcn_mfma_f32_16x16x32_bf16(af[i], bf[j], acc[i][j], 0, 0, 0);
        }
    }

    __syncthreads();
    unsigned short* T = smem + wv * 2304;      // per-wave [32][72]
    #pragma unroll
    for (int i = 0; i < 2; ++i)
        #pragma unroll
        for (int j = 0; j < 4; ++j) {
            float bv = bias[col0 + wn + j * 16 + l15];
            #pragma unroll
            for (int r = 0; r < 4; ++r)
                T[(i * 16 + quad * 4 + r) * 72 + j * 16 + l15] = bfbits(acc[i][j][r] + bv);
        }
    #pragma unroll
    for (int it = 0; it < 4; ++it) {
        int rr2 = it * 8 + (lane >> 3);
        int cc2 = (lane & 7) * 8;
        *(uint4*)&C[(size_t)(row0 + wm + rr2) * 512 + col0 + wn + cc2] =
            *(const uint4*)&T[rr2 * 72 + cc2];
    }
}

// ---------------------------------------------------------------------------
// MFMA distance attention, 32x32x16. Block = 4 waves (256 thr), 32 q/wave =
// 128 q per (b,h). Computes S^T = K.Q^T so C cols = q: per-lane scalar
// denominator, and P packed to LDS as b64 (consecutive keys per reg group).
// Each wave reads K/V tiles from LDS exactly once. bh = id & 63 (XCD-local).
// ---------------------------------------------------------------------------
__global__ __launch_bounds__(256) void attn_kernel(const unsigned short* __restrict__ Q,
                                                   const unsigned short* __restrict__ K,
                                                   const unsigned short* __restrict__ Vt,
                                                   const float* __restrict__ qsq,
                                                   const float* __restrict__ ksq,
                                                   unsigned short* __restrict__ O) {
    __shared__ unsigned short Ks[64 * 72];     // [key][d]
    __shared__ unsigned short Vs[64 * 72];     // [d][key]
    __shared__ unsigned short Ps[4][32 * 72];  // per-wave P [q][key]
    __shared__ float ksq_s[64];
    __shared__ float dinv_s[4][32];

    const int id = blockIdx.x;
    const int bh = id & 63, qb = id >> 6;      // qb 0..7
    const int q0 = qb * 128;
    const int tid = threadIdx.x;
    const int lane = tid & 63, w = tid >> 6;
    const int half = lane >> 5, l31 = lane & 31;
    const int b_ = bh >> 3, h_ = bh & 7;

    const unsigned short* Qb = Q  + (size_t)bh * N * DH;
    const unsigned short* Kb = K  + (size_t)bh * N * DH;
    const unsigned short* Vb = Vt + (size_t)bh * DH * N;

    const int qrow = q0 + w * 32 + l31;

    // Q fragments in registers: B-operand [n=q][k=d], lane n=l31, k=ks*16+half*8
    short8 qa[4];
    {
        const unsigned short* qp = Qb + (size_t)qrow * 64 + half * 8;
        #pragma unroll
        for (int ks = 0; ks < 4; ++ks) qa[ks] = *(const short8*)(qp + ks * 16);
    }
    const float qeps = qsq[bh * N + qrow] + EPS_DIST;

    f32x16 oacc[2];
    #pragma unroll
    for (int dt = 0; dt < 2; ++dt)
        #pragma unroll
        for (int r = 0; r < 16; ++r) oacc[dt][r] = 0.f;
    float dpart = 0.f;

    // staging: 256 threads, 2 x 16B each for K and V
    const int rr = tid >> 2, cc = (tid & 3) * 16;
    uint4 kreg0, kreg1, vreg0, vreg1;
    float ksreg = 0.f;

    kreg0 = *(const uint4*)(Kb + (size_t)rr * 64 + cc);
    kreg1 = *(const uint4*)(Kb + (size_t)rr * 64 + cc + 8);
    vreg0 = *(const uint4*)(Vb + (size_t)rr * N + cc);
    vreg1 = *(const uint4*)(Vb + (size_t)rr * N + cc + 8);
    if (tid < 64) ksreg = ksq[bh * N + tid];

    *(uint4*)&Ks[rr * 72 + cc]     = kreg0;
    *(uint4*)&Ks[rr * 72 + cc + 8] = kreg1;
    *(uint4*)&Vs[rr * 72 + cc]     = vreg0;
    *(uint4*)&Vs[rr * 72 + cc + 8] = vreg1;
    if (tid < 64) ksq_s[tid] = ksreg;
    __syncthreads();

    for (int kt = 0; kt < 16; ++kt) {
        if (kt < 15) {   // prefetch next tile into registers
            kreg0 = *(const uint4*)(Kb + (size_t)((kt + 1) * 64 + rr) * 64 + cc);
            kreg1 = *(const uint4*)(Kb + (size_t)((kt + 1) * 64 + rr) * 64 + cc + 8);
            vreg0 = *(const uint4*)(Vb + (size_t)rr * N + (kt + 1) * 64 + cc);
            vreg1 = *(const uint4*)(Vb + (size_t)rr * N + (kt + 1) * 64 + cc + 8);
            if (tid < 64) ksreg = ksq[bh * N + (kt + 1) * 64 + tid];
        }

        // S^T = K.Q^T: A = K-frag [m=key][k=d], B = Q-frag (registers)
        f32x16 sacc[2];
        #pragma unroll
        for (int kb = 0; kb < 2; ++kb)
            #pragma unroll
            for (int r = 0; r < 16; ++r) sacc[kb][r] = 0.f;
        #pragma unroll
        for (int ks = 0; ks < 4; ++ks) {
            short8 kf0 = *(const short8*)&Ks[(l31)      * 72 + ks * 16 + half * 8];
            short8 kf1 = *(const short8*)&Ks[(32 + l31) * 72 + ks * 16 + half * 8];
            sacc[0] = __builtin_amdgcn_mfma_f32_32x32x16_bf16(kf0, qa[ks], sacc[0], 0, 0, 0);
            sacc[1] = __builtin_amdgcn_mfma_f32_32x32x16_bf16(kf1, qa[ks], sacc[1], 0, 0, 0);
        }

        // transform: C col = q (= l31), row = key = (r&3) + 8*(r>>2) + 4*half
        #pragma unroll
        for (int kb = 0; kb < 2; ++kb) {
            #pragma unroll
            for (int g = 0; g < 4; ++g) {
                const int keyl = kb * 32 + 8 * g + 4 * half;
                float4 ks2v = *(const float4*)&ksq_s[keyl];
                union { float f; unsigned u; } p0, p1, p2, p3;
                {
                    float d2 = fmaf(-2.0f, sacc[kb][4 * g + 0], qeps + ks2v.x);
                    p0.f = __expf(-__builtin_amdgcn_sqrtf(fmaxf(d2, EPS_DIST)));
                    d2 = fmaf(-2.0f, sacc[kb][4 * g + 1], qeps + ks2v.y);
                    p1.f = __expf(-__builtin_amdgcn_sqrtf(fmaxf(d2, EPS_DIST)));
                    d2 = fmaf(-2.0f, sacc[kb][4 * g + 2], qeps + ks2v.z);
                    p2.f = __expf(-__builtin_amdgcn_sqrtf(fmaxf(d2, EPS_DIST)));
                    d2 = fmaf(-2.0f, sacc[kb][4 * g + 3], qeps + ks2v.w);
                    p3.f = __expf(-__builtin_amdgcn_sqrtf(fmaxf(d2, EPS_DIST)));
                }
                dpart += (p0.f + p1.f) + (p2.f + p3.f);
                uint2 pk;
                pk.x = __builtin_amdgcn_perm(p1.u, p0.u, 0x07060302);
                pk.y = __builtin_amdgcn_perm(p3.u, p2.u, 0x07060302);
                *(uint2*)&Ps[w][l31 * 72 + keyl] = pk;
            }
        }

        // PV: O[q][d] = P[q][key] . V^T[d][key];  A = P-frag, B = V-frag
        #pragma unroll
        for (int ks = 0; ks < 4; ++ks) {
            short8 pa  = *(const short8*)&Ps[w][l31 * 72 + ks * 16 + half * 8];
            short8 vf0 = *(const short8*)&Vs[(l31)      * 72 + ks * 16 + half * 8];
            short8 vf1 = *(const short8*)&Vs[(32 + l31) * 72 + ks * 16 + half * 8];
            oacc[0] = __builtin_amdgcn_mfma_f32_32x32x16_bf16(pa, vf0, oacc[0], 0, 0, 0);
            oacc[1] = __builtin_amdgcn_mfma_f32_32x32x16_bf16(pa, vf1, oacc[1], 0, 0, 0);
        }

        if (kt < 15) {
            __syncthreads();   // all waves done reading tile kt
            *(uint4*)&Ks[rr * 72 + cc]     = kreg0;
            *(uint4*)&Ks[rr * 72 + cc + 8] = kreg1;
            *(uint4*)&Vs[rr * 72 + cc]     = vreg0;
            *(uint4*)&Vs[rr * 72 + cc + 8] = vreg1;
            if (tid < 64) ksq_s[tid] = ksreg;
            __syncthreads();   // writes visible
        }
    }

    // denominator: lane pair (l31, l31+32) covers same q, disjoint keys
    dpart += __shfl_xor(dpart, 32, 64);
    if (half == 0) dinv_s[w][l31] = 1.0f / dpart;

    // O write: col = d = dt*32 + l31, row q = (r&3) + 8*(r>>2) + 4*half
    #pragma unroll
    for (int r = 0; r < 16; ++r) {
        const int lq = (r & 3) + 8 * (r >> 2) + 4 * half;
        const float rinv = dinv_s[w][lq];
        const int n_ = q0 + w * 32 + lq;
        unsigned short* og = O + ((size_t)(b_ * N + n_) * D) + h_ * DH;
        og[l31]      = bfbits(oacc[0][r] * rinv);
        og[32 + l31] = bfbits(oacc[1][r] * rinv);
    }
}

// ---------------------------------------------------------------------------
extern "C" void kernel_launch(void* const* d_in, const int* in_sizes, int n_in,
                              void* d_out, int out_size, void* d_ws, size_t ws_size,
                              hipStream_t stream) {
    const float* x     = (const float*)d_in[0];
    const float* Wq    = (const float*)d_in[1];
    const float* Wk    = (const float*)d_in[2];
    const float* Wv    = (const float*)d_in[3];
    const float* Wo    = (const float*)d_in[4];
    const float* bq    = (const float*)d_in[5];
    const float* bk    = (const float*)d_in[6];
    const float* bv    = (const float*)d_in[7];
    const float* bo    = (const float*)d_in[8];
    const float* ln1_g = (const float*)d_in[9];
    const float* ln1_b = (const float*)d_in[10];
    const float* ln2_g = (const float*)d_in[11];
    const float* ln2_b = (const float*)d_in[12];
    float* out = (float*)d_out;

    unsigned short* WtAll = (unsigned short*)d_ws;    // [4][512][512] bf16
    unsigned short* h_bf  = WtAll + 4 * 262144;       // [8192][512]
    unsigned short* Qb    = h_bf + 4194304;           // [64][1024][64]
    unsigned short* Kb    = Qb + 4194304;
    unsigned short* Vtg   = Kb + 4194304;             // [64][64][1024] transposed
    unsigned short* Ob    = Vtg + 4194304;            // [8192][512]
    unsigned short* Y0    = Ob + 4194304;             // [8192][512] bf16
    float* qsq = (float*)(Y0 + 4194304);              // [65536]
    float* ksq = qsq + 65536;

    // 1) weights -> bf16^T  +  LN1 -> bf16 (fused launch)
    prep_kernel<<<256 + M_ROWS, 256, 0, stream>>>(Wq, Wk, Wv, Wo, WtAll,
                                                  x, ln1_g, ln1_b, h_bf);

    // 2) fused QKV projection (N=1536) + scatter + sum-squares
    gemm_qkv<128><<<768, 256, 0, stream>>>(h_bf, WtAll, bq, bk, bv,
                                           Qb, Kb, Vtg, qsq, ksq);

    // 3) MFMA distance attention -> Ob [B,N,D] bf16 (512 blocks, 32x32 MFMA)
    attn_kernel<<<512, 256, 0, stream>>>(Qb, Kb, Vtg, qsq, ksq, Ob);

    // 4) output projection -> bf16 Y0
    gemm_out<<<512, 256, 0, stream>>>(Ob, WtAll + 3 * 262144, bo, Y0);

    // 5) residual + post-norm
    ln2_kernel<<<M_ROWS, 256, 0, stream>>>(Y0, x, ln2_g, ln2_b, out);
}